// Round 2
// baseline (466.695 us; speedup 1.0000x reference)
//
#include <hip/hip_runtime.h>
#include <hip/hip_fp16.h>
#include <stdint.h>

#define TOKENS 4096
#define HDIM   2048
#define IDIM   5632
#define BM 128
#define BN 128
#define BK 64

typedef _Float16 f16x8 __attribute__((ext_vector_type(8)));
typedef float    f32x4 __attribute__((ext_vector_type(4)));

// ---------- fp4 decode helpers (verified round 1) ----------
__device__ __forceinline__ uint32_t dec2(uint32_t z, uint32_t s2u) {
    uint32_t sgn = (z << 12) & 0x80008000u;
    uint32_t h   = ((z << 9) & 0x0E000E00u) | sgn;
    __half2 hv = __builtin_bit_cast(__half2, h);
    __half2 sv = __builtin_bit_cast(__half2, s2u);
    __half2 r  = __hmul2(hv, sv);
    return __builtin_bit_cast(uint32_t, r);
}
__device__ __forceinline__ int4 dec8(uint32_t w, uint32_t s2u) {
    int4 d;
    d.x = (int)dec2( w        & 0x000F000Fu, s2u);
    d.y = (int)dec2((w >> 4)  & 0x000F000Fu, s2u);
    d.z = (int)dec2((w >> 8)  & 0x000F000Fu, s2u);
    d.w = (int)dec2((w >> 12) & 0x000F000Fu, s2u);
    return d;
}
__device__ __forceinline__ uint32_t scale_s2u(float sc) {
    uint16_t hs = __builtin_bit_cast(uint16_t, __float2half(sc * 16384.0f));
    return (uint32_t)hs * 0x00010001u;
}
__device__ __forceinline__ uint32_t packh(float lo, float hi) {
    __half2 h2 = __halves2half2(__float2half(lo), __float2half(hi));
    return __builtin_bit_cast(uint32_t, h2);
}
__device__ __forceinline__ void gl_lds16(const void* g, void* l) {
    __builtin_amdgcn_global_load_lds(
        (const __attribute__((address_space(1))) uint32_t*)g,
        (__attribute__((address_space(3))) uint32_t*)l, 16, 0, 0);
}

// ---------- hidden fp32 -> f16, sigma k-order; optional tile pre-swizzle ----------
template<bool PRESWZ>
__global__ __launch_bounds__(256) void convert_hidden(
    const float* __restrict__ src, __half* __restrict__ dst)
{
    int idx = blockIdx.x * 256 + threadIdx.x;   // one 8-group per thread
    int m  = idx >> 8;                          // HDIM/8 = 256 groups/row
    int kb = idx & 255;
    const float4* s = (const float4*)src + (size_t)idx * 2;
    float4 a = s[0], b = s[1];
    int4 v;
    v.x = (int)packh(a.x, b.x);
    v.y = (int)packh(a.y, b.y);
    v.z = (int)packh(a.z, b.z);
    v.w = (int)packh(a.w, b.w);
    int slot = PRESWZ ? ((kb & 7) ^ (m & 7)) : (kb & 7);
    *(int4*)(dst + (size_t)m * HDIM + (kb & ~7) * 8 + slot * 8) = v;
}

// ---------- dequant W_gu -> f16, transposed [11264][2048], gate/up interleaved
// by 16 columns, sigma k-order, pre-swizzled 16B slots within each 64-k tile ----------
__global__ __launch_bounds__(256) void dequant_wgu(
    const uint32_t* __restrict__ W, const float* __restrict__ S,
    __half* __restrict__ Bt)
{
    int np = blockIdx.x * 256 + threadIdx.x;   // interleaved row 0..11263
    int within = np & 15;
    int pair = np >> 5;
    int sel  = (np >> 4) & 1;
    int sc = pair * 16 + within + (sel ? IDIM : 0);
    int x = np & 7;
    #pragma unroll
    for (int q = 0; q < 4; ++q) {
        int kt = blockIdx.y * 4 + q;
        uint32_t s2u = scale_s2u(S[(size_t)(kt >> 1) * (2 * IDIM) + sc]);
        #pragma unroll
        for (int g = 0; g < 8; ++g) {
            uint32_t w = W[(size_t)(kt * 8 + g) * (2 * IDIM) + sc];
            int4 d = dec8(w, s2u);
            *(int4*)(Bt + (size_t)np * HDIM + kt * 64 + ((g ^ x) << 3)) = d;
        }
    }
}

// ---------- GEMM1: 8-phase-style, 256x128 tile, 3 LDS buffers, counted vmcnt ----------
#define G1_BM 256
#define G1_BN 128
#define G1_BK 64
#define G1_NT (HDIM / G1_BK)   // 32

__global__ __launch_bounds__(512, 1) void gemm1_8ph(
    const __half* __restrict__ A, const __half* __restrict__ Bt,
    __half* __restrict__ act)
{
    __shared__ __half Al[3][G1_BM * G1_BK];   // 3 x 32 KB
    __shared__ __half Bl[3][G1_BN * G1_BK];   // 3 x 16 KB   (144 KB total)
    const int tid  = threadIdx.x;
    const int lane = tid & 63;
    const int wid  = tid >> 6;     // 0..7
    const int wm   = wid >> 2;     // 0..1
    const int wn   = wid & 3;      // 0..3

    int bid = blockIdx.x;
    int swz = (bid & 7) * (1408 / 8) + (bid >> 3);   // XCD-aware, bijective (1408%8==0)
    int by = swz / 88, bx = swz % 88;
    const int m0 = by * G1_BM;
    const int n0 = bx * G1_BN;

    // per-thread staging sources (kt=0); advance by kt*64 halves
    int ia0 = tid, ia1 = 512 + tid, ia2 = 1024 + tid, ia3 = 1536 + tid;
    const __half* preA0 = A + (size_t)(m0 + (ia0 >> 3)) * HDIM + (ia0 & 7) * 8;
    const __half* preA1 = A + (size_t)(m0 + (ia1 >> 3)) * HDIM + (ia1 & 7) * 8;
    const __half* preA2 = A + (size_t)(m0 + (ia2 >> 3)) * HDIM + (ia2 & 7) * 8;
    const __half* preA3 = A + (size_t)(m0 + (ia3 >> 3)) * HDIM + (ia3 & 7) * 8;
    const __half* preB0 = Bt + (size_t)(n0 + (ia0 >> 3)) * HDIM + (ia0 & 7) * 8;
    const __half* preB1 = Bt + (size_t)(n0 + (ia1 >> 3)) * HDIM + (ia1 & 7) * 8;

    auto stg3a = [&](int buf, int kt) {
        gl_lds16(preA0 + (size_t)kt * G1_BK, &Al[buf][(0    + wid * 64) * 8]);
        gl_lds16(preA1 + (size_t)kt * G1_BK, &Al[buf][(512  + wid * 64) * 8]);
        gl_lds16(preB0 + (size_t)kt * G1_BK, &Bl[buf][(0    + wid * 64) * 8]);
    };
    auto stg3b = [&](int buf, int kt) {
        gl_lds16(preA2 + (size_t)kt * G1_BK, &Al[buf][(1024 + wid * 64) * 8]);
        gl_lds16(preA3 + (size_t)kt * G1_BK, &Al[buf][(1536 + wid * 64) * 8]);
        gl_lds16(preB1 + (size_t)kt * G1_BK, &Bl[buf][(512  + wid * 64) * 8]);
    };

    f32x4 acc[8][2];
    #pragma unroll
    for (int i = 0; i < 8; ++i) {
        acc[i][0] = f32x4{0.f, 0.f, 0.f, 0.f};
        acc[i][1] = f32x4{0.f, 0.f, 0.f, 0.f};
    }

    auto phase = [&](const __half* Ac, const __half* Bc, int ks) {
        f16x8 af[8], bf[2];
        int kb = ks * 4 + (lane >> 4);
        #pragma unroll
        for (int mi = 0; mi < 8; ++mi) {
            int r = wm * 128 + mi * 16 + (lane & 15);
            af[mi] = *(const f16x8*)&Ac[r * 64 + ((kb ^ (r & 7)) << 3)];
        }
        #pragma unroll
        for (int ni = 0; ni < 2; ++ni) {
            int r = wn * 32 + ni * 16 + (lane & 15);
            bf[ni] = *(const f16x8*)&Bc[r * 64 + ((kb ^ (r & 7)) << 3)];
        }
        __builtin_amdgcn_s_setprio(1);
        #pragma unroll
        for (int mi = 0; mi < 8; ++mi)
            #pragma unroll
            for (int ni = 0; ni < 2; ++ni)
                acc[mi][ni] = __builtin_amdgcn_mfma_f32_16x16x32_f16(af[mi], bf[ni], acc[mi][ni], 0, 0, 0);
        __builtin_amdgcn_s_setprio(0);
    };

    // prologue: stage kt=0 and kt=1
    stg3a(0, 0); stg3b(0, 0);
    stg3a(1, 1); stg3b(1, 1);
    asm volatile("s_waitcnt vmcnt(6)" ::: "memory");   // kt=0 complete
    __builtin_amdgcn_s_barrier();

    for (int kt = 0; kt < G1_NT; ++kt) {
        int cur = kt % 3;
        int nxt = cur + 2; if (nxt >= 3) nxt -= 3;
        bool st = (kt + 2) < G1_NT;
        if (st) stg3a(nxt, kt + 2);
        phase(&Al[cur][0], &Bl[cur][0], 0);
        __builtin_amdgcn_s_barrier();
        if (st) stg3b(nxt, kt + 2);
        phase(&Al[cur][0], &Bl[cur][0], 1);
        // all this tile's ds_reads must be complete before any wave may
        // overwrite this buffer (next tile's stg3a targets buf[(kt+3)%3]=cur... 
        // targets rotate; enforced by this lgkmcnt + barrier)
        asm volatile("s_waitcnt lgkmcnt(0)" ::: "memory");
        if (kt < G1_NT - 2) asm volatile("s_waitcnt vmcnt(6)" ::: "memory");
        else                asm volatile("s_waitcnt vmcnt(0)" ::: "memory");
        __builtin_amdgcn_s_barrier();
    }

    // epilogue: silu(gate)*up -> act (sigma-permuted column slot)
    const int j0 = (bx * 4 + wn) * 16;
    int ja = j0 + (lane & 15);
    int colstore = (ja & ~7) | (((ja & 3) << 1) | ((ja >> 2) & 1));
    #pragma unroll
    for (int mi = 0; mi < 8; ++mi) {
        #pragma unroll
        for (int r = 0; r < 4; ++r) {
            int m = m0 + wm * 128 + mi * 16 + (lane >> 4) * 4 + r;
            float gv = acc[mi][0][r];
            float uv = acc[mi][1][r];
            float sig = 1.0f / (1.0f + __expf(-gv));
            act[(size_t)m * IDIM + colstore] = __float2half(gv * sig * uv);
        }
    }
}

// ---------- round-1 fused-decode GEMM1 (fallback if ws too small) ----------
__global__ __launch_bounds__(256, 2) void gemm1_silu(
    const __half* __restrict__ A, const uint32_t* __restrict__ W,
    const float* __restrict__ S, __half* __restrict__ act)
{
    __shared__ __half Alds[BM * BK];
    __shared__ __half Blds[2][BN * BK];
    const int tid  = threadIdx.x;
    const int lane = tid & 63;
    const int wid  = tid >> 6;
    const int wm = wid >> 1, wn = wid & 1;
    const int m0 = blockIdx.y * BM;
    const int c0 = blockIdx.x * BN;

    f32x4 accg[4][4], accu[4][4];
    #pragma unroll
    for (int i = 0; i < 4; ++i)
        #pragma unroll
        for (int j = 0; j < 4; ++j) {
            accg[i][j] = f32x4{0.f, 0.f, 0.f, 0.f};
            accu[i][j] = f32x4{0.f, 0.f, 0.f, 0.f};
        }

    const int c = tid & 127;
    const int rbase = (tid >> 7) * 4;

    for (int kt = 0; kt < HDIM / BK; ++kt) {
        const int k0 = kt * BK;
        #pragma unroll
        for (int i = 0; i < 4; ++i) {
            int u = tid + i * 256;
            int row = u >> 3, kb = u & 7;
            int4 v = *(const int4*)(A + (size_t)(m0 + row) * HDIM + k0 + kb * 8);
            *(int4*)((char*)Alds + row * 128 + ((kb ^ (row & 7)) << 4)) = v;
        }
        const int g = k0 >> 7;
        #pragma unroll
        for (int p = 0; p < 2; ++p) {
            const int ncol = (p ? IDIM : 0) + c0 + c;
            uint32_t s2u = scale_s2u(S[(size_t)g * (2 * IDIM) + ncol]);
            #pragma unroll
            for (int i = 0; i < 4; ++i) {
                int rl = rbase + i;
                uint32_t w = W[(size_t)(kt * 8 + rl) * (2 * IDIM) + ncol];
                int4 d = dec8(w, s2u);
                *(int4*)((char*)&Blds[p][0] + c * 128 + ((rl ^ (c & 7)) << 4)) = d;
            }
        }
        __syncthreads();
        #pragma unroll
        for (int ks = 0; ks < 2; ++ks) {
            f16x8 af[4], bg[4], bu[4];
            const int kb = ks * 4 + (lane >> 4);
            #pragma unroll
            for (int mi = 0; mi < 4; ++mi) {
                int m = wm * 64 + mi * 16 + (lane & 15);
                af[mi] = *(const f16x8*)((const char*)Alds + m * 128 + ((kb ^ (m & 7)) << 4));
            }
            #pragma unroll
            for (int ni = 0; ni < 4; ++ni) {
                int n = wn * 64 + ni * 16 + (lane & 15);
                bg[ni] = *(const f16x8*)((const char*)&Blds[0][0] + n * 128 + ((kb ^ (n & 7)) << 4));
                bu[ni] = *(const f16x8*)((const char*)&Blds[1][0] + n * 128 + ((kb ^ (n & 7)) << 4));
            }
            #pragma unroll
            for (int mi = 0; mi < 4; ++mi)
                #pragma unroll
                for (int ni = 0; ni < 4; ++ni) {
                    accg[mi][ni] = __builtin_amdgcn_mfma_f32_16x16x32_f16(af[mi], bg[ni], accg[mi][ni], 0, 0, 0);
                    accu[mi][ni] = __builtin_amdgcn_mfma_f32_16x16x32_f16(af[mi], bu[ni], accu[mi][ni], 0, 0, 0);
                }
        }
        __syncthreads();
    }
    #pragma unroll
    for (int mi = 0; mi < 4; ++mi) {
        #pragma unroll
        for (int ni = 0; ni < 4; ++ni) {
            int nlog = c0 + wn * 64 + ni * 16 + (lane & 15);
            int ncol = (nlog & ~7) | (((nlog & 3) << 1) | ((nlog >> 2) & 1));
            #pragma unroll
            for (int r = 0; r < 4; ++r) {
                int m = m0 + wm * 64 + mi * 16 + (lane >> 4) * 4 + r;
                float gv = accg[mi][ni][r];
                float uv = accu[mi][ni][r];
                float sig = 1.0f / (1.0f + __expf(-gv));
                act[(size_t)m * IDIM + ncol] = __float2half(gv * sig * uv);
            }
        }
    }
}

// ---------- GEMM2 (unchanged, fused decode): out = moe + act @ deq(Wd) ----------
__global__ __launch_bounds__(256, 2) void gemm2_add(
    const __half* __restrict__ A, const uint32_t* __restrict__ W,
    const float* __restrict__ S, const float* __restrict__ moe,
    float* __restrict__ out)
{
    __shared__ __half Alds[BM * BK];
    __shared__ __half Blds[BN * BK];
    const int tid  = threadIdx.x;
    const int lane = tid & 63;
    const int wid  = tid >> 6;
    const int wm = wid >> 1, wn = wid & 1;
    const int m0 = blockIdx.y * BM;
    const int n0 = blockIdx.x * BN;

    f32x4 acc[4][4];
    #pragma unroll
    for (int i = 0; i < 4; ++i)
        #pragma unroll
        for (int j = 0; j < 4; ++j) acc[i][j] = f32x4{0.f, 0.f, 0.f, 0.f};

    const int c = tid & 127;
    const int rbase = (tid >> 7) * 4;

    for (int kt = 0; kt < IDIM / BK; ++kt) {
        const int k0 = kt * BK;
        #pragma unroll
        for (int i = 0; i < 4; ++i) {
            int u = tid + i * 256;
            int row = u >> 3, kb = u & 7;
            int4 v = *(const int4*)(A + (size_t)(m0 + row) * IDIM + k0 + kb * 8);
            *(int4*)((char*)Alds + row * 128 + ((kb ^ (row & 7)) << 4)) = v;
        }
        {
            const int g = k0 >> 7;
            const int ncol = n0 + c;
            uint32_t s2u = scale_s2u(S[(size_t)g * HDIM + ncol]);
            #pragma unroll
            for (int i = 0; i < 4; ++i) {
                int rl = rbase + i;
                uint32_t w = W[(size_t)(kt * 8 + rl) * HDIM + ncol];
                int4 d = dec8(w, s2u);
                *(int4*)((char*)Blds + c * 128 + ((rl ^ (c & 7)) << 4)) = d;
            }
        }
        __syncthreads();
        #pragma unroll
        for (int ks = 0; ks < 2; ++ks) {
            f16x8 af[4], bf[4];
            const int kb = ks * 4 + (lane >> 4);
            #pragma unroll
            for (int mi = 0; mi < 4; ++mi) {
                int m = wm * 64 + mi * 16 + (lane & 15);
                af[mi] = *(const f16x8*)((const char*)Alds + m * 128 + ((kb ^ (m & 7)) << 4));
            }
            #pragma unroll
            for (int ni = 0; ni < 4; ++ni) {
                int n = wn * 64 + ni * 16 + (lane & 15);
                bf[ni] = *(const f16x8*)((const char*)Blds + n * 128 + ((kb ^ (n & 7)) << 4));
            }
            #pragma unroll
            for (int mi = 0; mi < 4; ++mi)
                #pragma unroll
                for (int ni = 0; ni < 4; ++ni)
                    acc[mi][ni] = __builtin_amdgcn_mfma_f32_16x16x32_f16(af[mi], bf[ni], acc[mi][ni], 0, 0, 0);
        }
        __syncthreads();
    }
    #pragma unroll
    for (int mi = 0; mi < 4; ++mi) {
        #pragma unroll
        for (int ni = 0; ni < 4; ++ni) {
            int n = n0 + wn * 64 + ni * 16 + (lane & 15);
            #pragma unroll
            for (int r = 0; r < 4; ++r) {
                int m = m0 + wm * 64 + mi * 16 + (lane >> 4) * 4 + r;
                out[(size_t)m * HDIM + n] = moe[(size_t)m * HDIM + n] + acc[mi][ni][r];
            }
        }
    }
}

extern "C" void kernel_launch(void* const* d_in, const int* in_sizes, int n_in,
                              void* d_out, int out_size, void* d_ws, size_t ws_size,
                              hipStream_t stream) {
    const float*    hidden = (const float*)d_in[0];
    const float*    moe    = (const float*)d_in[1];
    const uint32_t* wgu    = (const uint32_t*)d_in[2];
    const float*    sgu    = (const float*)d_in[3];
    const uint32_t* wd     = (const uint32_t*)d_in[4];
    const float*    sd     = (const float*)d_in[5];
    float* out = (float*)d_out;

    __half* hidden_f16 = (__half*)d_ws;                                      // 16.78 MB
    __half* act        = (__half*)((char*)d_ws + (size_t)TOKENS * HDIM * 2); // 46.14 MB
    size_t need = (size_t)TOKENS * HDIM * 2 + (size_t)TOKENS * IDIM * 2
                + (size_t)HDIM * (2 * IDIM) * 2;                             // 109 MB

    if (ws_size >= need) {
        __half* wgu16 = (__half*)((char*)d_ws + (size_t)TOKENS * HDIM * 2
                                              + (size_t)TOKENS * IDIM * 2);  // 46.14 MB
        convert_hidden<true><<<dim3(TOKENS * HDIM / 8 / 256), dim3(256), 0, stream>>>(hidden, hidden_f16);
        dequant_wgu<<<dim3(2 * IDIM / 256, 8), dim3(256), 0, stream>>>(wgu, sgu, wgu16);
        gemm1_8ph<<<dim3(1408), dim3(512), 0, stream>>>(hidden_f16, wgu16, act);
    } else {
        convert_hidden<false><<<dim3(TOKENS * HDIM / 8 / 256), dim3(256), 0, stream>>>(hidden, hidden_f16);
        gemm1_silu<<<dim3(IDIM / BN, TOKENS / BM), dim3(256), 0, stream>>>(hidden_f16, wgu, sgu, act);
    }
    gemm2_add<<<dim3(HDIM / BN, TOKENS / BM), dim3(256), 0, stream>>>(act, wd, sd, moe, out);
}

// Round 3
// 370.311 us; speedup vs baseline: 1.2603x; 1.2603x over previous
//
#include <hip/hip_runtime.h>
#include <hip/hip_fp16.h>
#include <stdint.h>

#define TOKENS 4096
#define HDIM   2048
#define IDIM   5632
#define BM 128
#define BN 128
#define BK 64

typedef _Float16 f16x8 __attribute__((ext_vector_type(8)));
typedef float    f32x4 __attribute__((ext_vector_type(4)));

// ---------- fp4 decode helpers (verified rounds 1-2) ----------
__device__ __forceinline__ uint32_t dec2(uint32_t z, uint32_t s2u) {
    uint32_t sgn = (z << 12) & 0x80008000u;
    uint32_t h   = ((z << 9) & 0x0E000E00u) | sgn;
    __half2 hv = __builtin_bit_cast(__half2, h);
    __half2 sv = __builtin_bit_cast(__half2, s2u);
    __half2 r  = __hmul2(hv, sv);
    return __builtin_bit_cast(uint32_t, r);
}
__device__ __forceinline__ int4 dec8(uint32_t w, uint32_t s2u) {
    int4 d;
    d.x = (int)dec2( w        & 0x000F000Fu, s2u);
    d.y = (int)dec2((w >> 4)  & 0x000F000Fu, s2u);
    d.z = (int)dec2((w >> 8)  & 0x000F000Fu, s2u);
    d.w = (int)dec2((w >> 12) & 0x000F000Fu, s2u);
    return d;
}
__device__ __forceinline__ uint32_t scale_s2u(float sc) {
    uint16_t hs = __builtin_bit_cast(uint16_t, __float2half(sc * 16384.0f));
    return (uint32_t)hs * 0x00010001u;
}
__device__ __forceinline__ uint32_t packh(float lo, float hi) {
    __half2 h2 = __halves2half2(__float2half(lo), __float2half(hi));
    return __builtin_bit_cast(uint32_t, h2);
}
__device__ __forceinline__ void gl_lds16(const void* g, void* l) {
    __builtin_amdgcn_global_load_lds(
        (const __attribute__((address_space(1))) uint32_t*)g,
        (__attribute__((address_space(3))) uint32_t*)l, 16, 0, 0);
}

// ---------- hidden fp32 -> f16, sigma k-order; optional tile pre-swizzle ----------
template<bool PRESWZ>
__global__ __launch_bounds__(256) void convert_hidden(
    const float* __restrict__ src, __half* __restrict__ dst)
{
    int idx = blockIdx.x * 256 + threadIdx.x;   // one 8-group per thread
    int m  = idx >> 8;                          // HDIM/8 = 256 groups/row
    int kb = idx & 255;
    const float4* s = (const float4*)src + (size_t)idx * 2;
    float4 a = s[0], b = s[1];
    int4 v;
    v.x = (int)packh(a.x, b.x);
    v.y = (int)packh(a.y, b.y);
    v.z = (int)packh(a.z, b.z);
    v.w = (int)packh(a.w, b.w);
    int slot = PRESWZ ? ((kb & 7) ^ (m & 7)) : (kb & 7);
    *(int4*)(dst + (size_t)m * HDIM + (kb & ~7) * 8 + slot * 8) = v;
}

// ---------- dequant W_gu -> f16, transposed [11264][2048], gate/up interleaved
// by 16 columns, sigma k-order, pre-swizzled 16B slots within each 64-k tile ----------
__global__ __launch_bounds__(256) void dequant_wgu(
    const uint32_t* __restrict__ W, const float* __restrict__ S,
    __half* __restrict__ Bt)
{
    int np = blockIdx.x * 256 + threadIdx.x;   // interleaved row 0..11263
    int within = np & 15;
    int pair = np >> 5;
    int sel  = (np >> 4) & 1;
    int sc = pair * 16 + within + (sel ? IDIM : 0);
    int x = np & 7;
    #pragma unroll
    for (int q = 0; q < 4; ++q) {
        int kt = blockIdx.y * 4 + q;
        uint32_t s2u = scale_s2u(S[(size_t)(kt >> 1) * (2 * IDIM) + sc]);
        #pragma unroll
        for (int g = 0; g < 8; ++g) {
            uint32_t w = W[(size_t)(kt * 8 + g) * (2 * IDIM) + sc];
            int4 d = dec8(w, s2u);
            *(int4*)(Bt + (size_t)np * HDIM + kt * 64 + ((g ^ x) << 3)) = d;
        }
    }
}

// ---------- GEMM1: 256x128 tile, 8 waves (64x64 each), 3 K-tile LDS buffers,
// stage distance 2, counted vmcnt(6), two 16-MFMA phases per K-tile ----------
#define G1_BM 256
#define G1_BN 128
#define G1_NT 32   // HDIM / 64

__global__ __launch_bounds__(512, 1) void gemm1_3buf(
    const __half* __restrict__ A, const __half* __restrict__ Bt,
    __half* __restrict__ act)
{
    __shared__ __half Al[3][G1_BM * 64];   // 3 x 32 KB
    __shared__ __half Bl[3][G1_BN * 64];   // 3 x 16 KB  (144 KB)
    const int tid  = threadIdx.x;
    const int lane = tid & 63;
    const int wid  = tid >> 6;
    const int wm   = wid >> 1;   // 0..3  (rows wm*64)
    const int wn   = wid & 1;    // 0..1  (cols wn*64)

    int bid = blockIdx.x;
    int swz = (bid & 7) * (1408 / 8) + (bid >> 3);   // bijective, 1408%8==0
    int by = swz / 88, bx = swz % 88;
    const int m0 = by * G1_BM;
    const int n0 = bx * G1_BN;

    const __half* pA0 = A  + (size_t)(m0 +   0 + (tid >> 3)) * HDIM + (tid & 7) * 8;
    const __half* pA1 = A  + (size_t)(m0 +  64 + (tid >> 3)) * HDIM + (tid & 7) * 8;
    const __half* pA2 = A  + (size_t)(m0 + 128 + (tid >> 3)) * HDIM + (tid & 7) * 8;
    const __half* pA3 = A  + (size_t)(m0 + 192 + (tid >> 3)) * HDIM + (tid & 7) * 8;
    const __half* pB0 = Bt + (size_t)(n0 +   0 + (tid >> 3)) * HDIM + (tid & 7) * 8;
    const __half* pB1 = Bt + (size_t)(n0 +  64 + (tid >> 3)) * HDIM + (tid & 7) * 8;

    auto stgA = [&](int buf, int kt) {
        gl_lds16(pA0 + (size_t)kt * 64, &Al[buf][(0    + wid * 64) * 8]);
        gl_lds16(pA1 + (size_t)kt * 64, &Al[buf][(512  + wid * 64) * 8]);
        gl_lds16(pA2 + (size_t)kt * 64, &Al[buf][(1024 + wid * 64) * 8]);
        gl_lds16(pA3 + (size_t)kt * 64, &Al[buf][(1536 + wid * 64) * 8]);
    };
    auto stgB = [&](int buf, int kt) {
        gl_lds16(pB0 + (size_t)kt * 64, &Bl[buf][(0    + wid * 64) * 8]);
        gl_lds16(pB1 + (size_t)kt * 64, &Bl[buf][(512  + wid * 64) * 8]);
    };

    f32x4 acc[4][4];
    #pragma unroll
    for (int i = 0; i < 4; ++i)
        #pragma unroll
        for (int j = 0; j < 4; ++j) acc[i][j] = f32x4{0.f, 0.f, 0.f, 0.f};

    // prologue: stage K-tiles 0,1 (12 loads); wait for tile 0 (leave 6 in flight)
    stgA(0, 0); stgB(0, 0);
    stgA(1, 1); stgB(1, 1);
    asm volatile("s_waitcnt vmcnt(6)" ::: "memory");
    asm volatile("s_barrier" ::: "memory");

    for (int kt = 0; kt < G1_NT; ++kt) {
        int cur = kt % 3;
        int nxt = cur + 2; if (nxt >= 3) nxt -= 3;
        const bool st = (kt + 2) < G1_NT;
        const __half* Ac = &Al[cur][0];
        const __half* Bc = &Bl[cur][0];

        // ---- phase A: read A(mi 0-1) + all B frags; stage A(kt+2); MFMA 16 ----
        f16x8 a[2][2], b[4][2];
        #pragma unroll
        for (int mi = 0; mi < 2; ++mi)
            #pragma unroll
            for (int kk = 0; kk < 2; ++kk) {
                int r  = wm * 64 + mi * 16 + (lane & 15);
                int kb = kk * 4 + (lane >> 4);
                a[mi][kk] = *(const f16x8*)&Ac[r * 64 + ((kb ^ (r & 7)) << 3)];
            }
        #pragma unroll
        for (int ni = 0; ni < 4; ++ni)
            #pragma unroll
            for (int kk = 0; kk < 2; ++kk) {
                int r  = wn * 64 + ni * 16 + (lane & 15);
                int kb = kk * 4 + (lane >> 4);
                b[ni][kk] = *(const f16x8*)&Bc[r * 64 + ((kb ^ (r & 7)) << 3)];
            }
        if (st) stgA(nxt, kt + 2);
        asm volatile("s_barrier" ::: "memory");
        asm volatile("s_waitcnt lgkmcnt(0)" ::: "memory");
        __builtin_amdgcn_sched_barrier(0);
        __builtin_amdgcn_s_setprio(1);
        #pragma unroll
        for (int mi = 0; mi < 2; ++mi)
            #pragma unroll
            for (int ni = 0; ni < 4; ++ni)
                #pragma unroll
                for (int kk = 0; kk < 2; ++kk)
                    acc[mi][ni] = __builtin_amdgcn_mfma_f32_16x16x32_f16(a[mi][kk], b[ni][kk], acc[mi][ni], 0, 0, 0);
        __builtin_amdgcn_s_setprio(0);
        asm volatile("s_barrier" ::: "memory");

        // ---- phase B: read A(mi 2-3); stage B(kt+2); MFMA 16; vmcnt(6) ----
        f16x8 a2[2][2];
        #pragma unroll
        for (int mi = 0; mi < 2; ++mi)
            #pragma unroll
            for (int kk = 0; kk < 2; ++kk) {
                int r  = wm * 64 + (mi + 2) * 16 + (lane & 15);
                int kb = kk * 4 + (lane >> 4);
                a2[mi][kk] = *(const f16x8*)&Ac[r * 64 + ((kb ^ (r & 7)) << 3)];
            }
        if (st) stgB(nxt, kt + 2);
        asm volatile("s_barrier" ::: "memory");
        asm volatile("s_waitcnt lgkmcnt(0)" ::: "memory");
        __builtin_amdgcn_sched_barrier(0);
        __builtin_amdgcn_s_setprio(1);
        #pragma unroll
        for (int mi = 0; mi < 2; ++mi)
            #pragma unroll
            for (int ni = 0; ni < 4; ++ni)
                #pragma unroll
                for (int kk = 0; kk < 2; ++kk)
                    acc[mi + 2][ni] = __builtin_amdgcn_mfma_f32_16x16x32_f16(a2[mi][kk], b[ni][kk], acc[mi + 2][ni], 0, 0, 0);
        __builtin_amdgcn_s_setprio(0);
        if (st) asm volatile("s_waitcnt vmcnt(6)" ::: "memory");
        else    asm volatile("s_waitcnt vmcnt(0)" ::: "memory");
        asm volatile("s_barrier" ::: "memory");
    }

    // epilogue: silu(gate)*up -> act (gate = ni even, up = ni odd; sigma col slot)
    #pragma unroll
    for (int mi = 0; mi < 4; ++mi) {
        #pragma unroll
        for (int q = 0; q < 2; ++q) {
            int ip = ((n0 + wn * 64) >> 5) + q;
            int gcol = ip * 16 + (lane & 15);
            int colstore = (gcol & ~7) | (((gcol & 3) << 1) | ((gcol >> 2) & 1));
            #pragma unroll
            for (int r = 0; r < 4; ++r) {
                int m = m0 + wm * 64 + mi * 16 + (lane >> 4) * 4 + r;
                float gv = acc[mi][2 * q][r];
                float uv = acc[mi][2 * q + 1][r];
                float sig = 1.0f / (1.0f + __expf(-gv));
                act[(size_t)m * IDIM + colstore] = __float2half(gv * sig * uv);
            }
        }
    }
}

// ---------- round-1 fused-decode GEMM1 (fallback if ws too small) ----------
__global__ __launch_bounds__(256, 2) void gemm1_silu(
    const __half* __restrict__ A, const uint32_t* __restrict__ W,
    const float* __restrict__ S, __half* __restrict__ act)
{
    __shared__ __half Alds[BM * BK];
    __shared__ __half Blds[2][BN * BK];
    const int tid  = threadIdx.x;
    const int lane = tid & 63;
    const int wid  = tid >> 6;
    const int wm = wid >> 1, wn = wid & 1;
    const int m0 = blockIdx.y * BM;
    const int c0 = blockIdx.x * BN;

    f32x4 accg[4][4], accu[4][4];
    #pragma unroll
    for (int i = 0; i < 4; ++i)
        #pragma unroll
        for (int j = 0; j < 4; ++j) {
            accg[i][j] = f32x4{0.f, 0.f, 0.f, 0.f};
            accu[i][j] = f32x4{0.f, 0.f, 0.f, 0.f};
        }

    const int c = tid & 127;
    const int rbase = (tid >> 7) * 4;

    for (int kt = 0; kt < HDIM / BK; ++kt) {
        const int k0 = kt * BK;
        #pragma unroll
        for (int i = 0; i < 4; ++i) {
            int u = tid + i * 256;
            int row = u >> 3, kb = u & 7;
            int4 v = *(const int4*)(A + (size_t)(m0 + row) * HDIM + k0 + kb * 8);
            *(int4*)((char*)Alds + row * 128 + ((kb ^ (row & 7)) << 4)) = v;
        }
        const int g = k0 >> 7;
        #pragma unroll
        for (int p = 0; p < 2; ++p) {
            const int ncol = (p ? IDIM : 0) + c0 + c;
            uint32_t s2u = scale_s2u(S[(size_t)g * (2 * IDIM) + ncol]);
            #pragma unroll
            for (int i = 0; i < 4; ++i) {
                int rl = rbase + i;
                uint32_t w = W[(size_t)(kt * 8 + rl) * (2 * IDIM) + ncol];
                int4 d = dec8(w, s2u);
                *(int4*)((char*)&Blds[p][0] + c * 128 + ((rl ^ (c & 7)) << 4)) = d;
            }
        }
        __syncthreads();
        #pragma unroll
        for (int ks = 0; ks < 2; ++ks) {
            f16x8 af[4], bg[4], bu[4];
            const int kb = ks * 4 + (lane >> 4);
            #pragma unroll
            for (int mi = 0; mi < 4; ++mi) {
                int m = wm * 64 + mi * 16 + (lane & 15);
                af[mi] = *(const f16x8*)((const char*)Alds + m * 128 + ((kb ^ (m & 7)) << 4));
            }
            #pragma unroll
            for (int ni = 0; ni < 4; ++ni) {
                int n = wn * 64 + ni * 16 + (lane & 15);
                bg[ni] = *(const f16x8*)((const char*)&Blds[0][0] + n * 128 + ((kb ^ (n & 7)) << 4));
                bu[ni] = *(const f16x8*)((const char*)&Blds[1][0] + n * 128 + ((kb ^ (n & 7)) << 4));
            }
            #pragma unroll
            for (int mi = 0; mi < 4; ++mi)
                #pragma unroll
                for (int ni = 0; ni < 4; ++ni) {
                    accg[mi][ni] = __builtin_amdgcn_mfma_f32_16x16x32_f16(af[mi], bg[ni], accg[mi][ni], 0, 0, 0);
                    accu[mi][ni] = __builtin_amdgcn_mfma_f32_16x16x32_f16(af[mi], bu[ni], accu[mi][ni], 0, 0, 0);
                }
        }
        __syncthreads();
    }
    #pragma unroll
    for (int mi = 0; mi < 4; ++mi) {
        #pragma unroll
        for (int ni = 0; ni < 4; ++ni) {
            int nlog = c0 + wn * 64 + ni * 16 + (lane & 15);
            int ncol = (nlog & ~7) | (((nlog & 3) << 1) | ((nlog >> 2) & 1));
            #pragma unroll
            for (int r = 0; r < 4; ++r) {
                int m = m0 + wm * 64 + mi * 16 + (lane >> 4) * 4 + r;
                float gv = accg[mi][ni][r];
                float uv = accu[mi][ni][r];
                float sig = 1.0f / (1.0f + __expf(-gv));
                act[(size_t)m * IDIM + ncol] = __float2half(gv * sig * uv);
            }
        }
    }
}

// ---------- GEMM2 (unchanged, fused decode): out = moe + act @ deq(Wd) ----------
__global__ __launch_bounds__(256, 2) void gemm2_add(
    const __half* __restrict__ A, const uint32_t* __restrict__ W,
    const float* __restrict__ S, const float* __restrict__ moe,
    float* __restrict__ out)
{
    __shared__ __half Alds[BM * BK];
    __shared__ __half Blds[BN * BK];
    const int tid  = threadIdx.x;
    const int lane = tid & 63;
    const int wid  = tid >> 6;
    const int wm = wid >> 1, wn = wid & 1;
    const int m0 = blockIdx.y * BM;
    const int n0 = blockIdx.x * BN;

    f32x4 acc[4][4];
    #pragma unroll
    for (int i = 0; i < 4; ++i)
        #pragma unroll
        for (int j = 0; j < 4; ++j) acc[i][j] = f32x4{0.f, 0.f, 0.f, 0.f};

    const int c = tid & 127;
    const int rbase = (tid >> 7) * 4;

    for (int kt = 0; kt < IDIM / BK; ++kt) {
        const int k0 = kt * BK;
        #pragma unroll
        for (int i = 0; i < 4; ++i) {
            int u = tid + i * 256;
            int row = u >> 3, kb = u & 7;
            int4 v = *(const int4*)(A + (size_t)(m0 + row) * IDIM + k0 + kb * 8);
            *(int4*)((char*)Alds + row * 128 + ((kb ^ (row & 7)) << 4)) = v;
        }
        {
            const int g = k0 >> 7;
            const int ncol = n0 + c;
            uint32_t s2u = scale_s2u(S[(size_t)g * HDIM + ncol]);
            #pragma unroll
            for (int i = 0; i < 4; ++i) {
                int rl = rbase + i;
                uint32_t w = W[(size_t)(kt * 8 + rl) * HDIM + ncol];
                int4 d = dec8(w, s2u);
                *(int4*)((char*)Blds + c * 128 + ((rl ^ (c & 7)) << 4)) = d;
            }
        }
        __syncthreads();
        #pragma unroll
        for (int ks = 0; ks < 2; ++ks) {
            f16x8 af[4], bf[4];
            const int kb = ks * 4 + (lane >> 4);
            #pragma unroll
            for (int mi = 0; mi < 4; ++mi) {
                int m = wm * 64 + mi * 16 + (lane & 15);
                af[mi] = *(const f16x8*)((const char*)Alds + m * 128 + ((kb ^ (m & 7)) << 4));
            }
            #pragma unroll
            for (int ni = 0; ni < 4; ++ni) {
                int n = wn * 64 + ni * 16 + (lane & 15);
                bf[ni] = *(const f16x8*)((const char*)Blds + n * 128 + ((kb ^ (n & 7)) << 4));
            }
            #pragma unroll
            for (int mi = 0; mi < 4; ++mi)
                #pragma unroll
                for (int ni = 0; ni < 4; ++ni)
                    acc[mi][ni] = __builtin_amdgcn_mfma_f32_16x16x32_f16(af[mi], bf[ni], acc[mi][ni], 0, 0, 0);
        }
        __syncthreads();
    }
    #pragma unroll
    for (int mi = 0; mi < 4; ++mi) {
        #pragma unroll
        for (int ni = 0; ni < 4; ++ni) {
            int n = n0 + wn * 64 + ni * 16 + (lane & 15);
            #pragma unroll
            for (int r = 0; r < 4; ++r) {
                int m = m0 + wm * 64 + mi * 16 + (lane >> 4) * 4 + r;
                out[(size_t)m * HDIM + n] = moe[(size_t)m * HDIM + n] + acc[mi][ni][r];
            }
        }
    }
}

extern "C" void kernel_launch(void* const* d_in, const int* in_sizes, int n_in,
                              void* d_out, int out_size, void* d_ws, size_t ws_size,
                              hipStream_t stream) {
    const float*    hidden = (const float*)d_in[0];
    const float*    moe    = (const float*)d_in[1];
    const uint32_t* wgu    = (const uint32_t*)d_in[2];
    const float*    sgu    = (const float*)d_in[3];
    const uint32_t* wd     = (const uint32_t*)d_in[4];
    const float*    sd     = (const float*)d_in[5];
    float* out = (float*)d_out;

    __half* hidden_f16 = (__half*)d_ws;                                      // 16.78 MB
    __half* act        = (__half*)((char*)d_ws + (size_t)TOKENS * HDIM * 2); // 46.14 MB
    size_t need = (size_t)TOKENS * HDIM * 2 + (size_t)TOKENS * IDIM * 2
                + (size_t)HDIM * (2 * IDIM) * 2;                             // 109 MB

    if (ws_size >= need) {
        __half* wgu16 = (__half*)((char*)d_ws + (size_t)TOKENS * HDIM * 2
                                              + (size_t)TOKENS * IDIM * 2);  // 46.14 MB
        convert_hidden<true><<<dim3(TOKENS * HDIM / 8 / 256), dim3(256), 0, stream>>>(hidden, hidden_f16);
        dequant_wgu<<<dim3(2 * IDIM / 256, 8), dim3(256), 0, stream>>>(wgu, sgu, wgu16);
        gemm1_3buf<<<dim3(1408), dim3(512), 0, stream>>>(hidden_f16, wgu16, act);
    } else {
        convert_hidden<false><<<dim3(TOKENS * HDIM / 8 / 256), dim3(256), 0, stream>>>(hidden, hidden_f16);
        gemm1_silu<<<dim3(IDIM / BN, TOKENS / BM), dim3(256), 0, stream>>>(hidden_f16, wgu, sgu, act);
    }
    gemm2_add<<<dim3(HDIM / BN, TOKENS / BM), dim3(256), 0, stream>>>(act, wd, sd, moe, out);
}

// Round 4
// 369.159 us; speedup vs baseline: 1.2642x; 1.0031x over previous
//
#include <hip/hip_runtime.h>
#include <hip/hip_fp16.h>
#include <stdint.h>

#define TOKENS 4096
#define HDIM   2048
#define IDIM   5632
#define BM 128
#define BN 128
#define BK 64

#define G1_NP  11264
#define G1_KSB (G1_NP * 64)   // halves per K-tile panel of Bt

typedef _Float16 f16x8 __attribute__((ext_vector_type(8)));
typedef float    f32x4 __attribute__((ext_vector_type(4)));

// ---------- fp4 decode helpers (verified rounds 1-3) ----------
__device__ __forceinline__ uint32_t dec2(uint32_t z, uint32_t s2u) {
    uint32_t sgn = (z << 12) & 0x80008000u;
    uint32_t h   = ((z << 9) & 0x0E000E00u) | sgn;
    __half2 hv = __builtin_bit_cast(__half2, h);
    __half2 sv = __builtin_bit_cast(__half2, s2u);
    __half2 r  = __hmul2(hv, sv);
    return __builtin_bit_cast(uint32_t, r);
}
__device__ __forceinline__ int4 dec8(uint32_t w, uint32_t s2u) {
    int4 d;
    d.x = (int)dec2( w        & 0x000F000Fu, s2u);
    d.y = (int)dec2((w >> 4)  & 0x000F000Fu, s2u);
    d.z = (int)dec2((w >> 8)  & 0x000F000Fu, s2u);
    d.w = (int)dec2((w >> 12) & 0x000F000Fu, s2u);
    return d;
}
__device__ __forceinline__ uint32_t scale_s2u(float sc) {
    uint16_t hs = __builtin_bit_cast(uint16_t, __float2half(sc * 16384.0f));
    return (uint32_t)hs * 0x00010001u;
}
__device__ __forceinline__ uint32_t packh(float lo, float hi) {
    __half2 h2 = __halves2half2(__float2half(lo), __float2half(hi));
    return __builtin_bit_cast(uint32_t, h2);
}
__device__ __forceinline__ void gl_lds16(const void* g, void* l) {
    __builtin_amdgcn_global_load_lds(
        (const __attribute__((address_space(1))) uint32_t*)g,
        (__attribute__((address_space(3))) uint32_t*)l, 16, 0, 0);
}

// ---------- hidden fp32 -> f16, sigma k-order; optional tile pre-swizzle ----------
template<bool PRESWZ>
__global__ __launch_bounds__(256) void convert_hidden(
    const float* __restrict__ src, __half* __restrict__ dst)
{
    int idx = blockIdx.x * 256 + threadIdx.x;   // one 8-group per thread
    int m  = idx >> 8;                          // HDIM/8 = 256 groups/row
    int kb = idx & 255;
    const float4* s = (const float4*)src + (size_t)idx * 2;
    float4 a = s[0], b = s[1];
    int4 v;
    v.x = (int)packh(a.x, b.x);
    v.y = (int)packh(a.y, b.y);
    v.z = (int)packh(a.z, b.z);
    v.w = (int)packh(a.w, b.w);
    int slot = PRESWZ ? ((kb & 7) ^ (m & 7)) : (kb & 7);
    *(int4*)(dst + (size_t)m * HDIM + (kb & ~7) * 8 + slot * 8) = v;
}

// ---------- dequant W_gu -> f16, K-tile-panel layout Bt[32][11264][64]:
// gate/up interleaved by 16 cols, sigma k-order, pre-swizzled 16B slots.
// Coalesced reads (64 consecutive words/wave per g) and contiguous 128B writes. ----------
__global__ __launch_bounds__(256) void dequant_wgu(
    const uint32_t* __restrict__ W, const float* __restrict__ S,
    __half* __restrict__ Bt)
{
    int np = blockIdx.x * 256 + threadIdx.x;   // interleaved row 0..11263
    int kt = blockIdx.y;                        // 0..31
    int within = np & 15;
    int pair = np >> 5;
    int sel  = (np >> 4) & 1;
    int sc = pair * 16 + within + (sel ? IDIM : 0);
    int x = np & 7;
    uint32_t s2u = scale_s2u(S[(size_t)(kt >> 1) * (2 * IDIM) + sc]);
    uint32_t w[8];
    #pragma unroll
    for (int g = 0; g < 8; ++g)
        w[g] = W[(size_t)(kt * 8 + g) * (2 * IDIM) + sc];
    __half* dst = Bt + (size_t)kt * G1_KSB + (size_t)np * 64;
    #pragma unroll
    for (int s = 0; s < 8; ++s) {
        int4 d = dec8(w[s ^ x], s2u);           // slot s holds logical word s^x... inverse: data(slot s)=word s^x? word g lands at slot g^x ⇔ slot s holds word s^x
        *(int4*)(dst + s * 8) = d;
    }
}

// ---------- GEMM1: m201-style 256x256 tile, 8 waves (128x64 each),
// 4 quadrant-phases per K-tile, double-buffered LDS, vmcnt(8) once per K-tile ----------
__global__ __launch_bounds__(512, 2) void gemm1_8ph(
    const __half* __restrict__ A, const __half* __restrict__ Bt,
    __half* __restrict__ act)
{
    __shared__ __half Al[2][256 * 64];   // 2 x 32 KB
    __shared__ __half Bl[2][256 * 64];   // 2 x 32 KB   (128 KB)
    const int tid  = threadIdx.x;
    const int lane = tid & 63;
    const int wid  = tid >> 6;
    const int wm   = wid >> 2;   // 0..1 : rows wm*128
    const int wn   = wid & 3;    // 0..3 : B rows wn*64

    int bid = blockIdx.x;
    int swz = (bid & 7) * 88 + (bid >> 3);   // 704 blocks, bijective
    int by = swz / 44, bx = swz % 44;
    const int m0 = by * 256;
    const int n0 = bx * 256;

    const __half* pAsrc = A  + (size_t)(m0 + (tid >> 3)) * HDIM + (tid & 7) * 8;
    const __half* pBsrc = Bt + (size_t)(n0 + (tid >> 3)) * 64 + (tid & 7) * 8;

    auto stageA = [&](int buf, int kt) {
        const __half* s = pAsrc + kt * 64;
        gl_lds16(s,                      &Al[buf][(0   + wid * 8) * 64]);
        gl_lds16(s + (size_t)64  * HDIM, &Al[buf][(64  + wid * 8) * 64]);
        gl_lds16(s + (size_t)128 * HDIM, &Al[buf][(128 + wid * 8) * 64]);
        gl_lds16(s + (size_t)192 * HDIM, &Al[buf][(192 + wid * 8) * 64]);
    };
    auto stageB = [&](int buf, int kt) {
        const __half* s = pBsrc + (size_t)kt * G1_KSB;
        gl_lds16(s,            &Bl[buf][(0   + wid * 8) * 64]);
        gl_lds16(s + 64  * 64, &Bl[buf][(64  + wid * 8) * 64]);
        gl_lds16(s + 128 * 64, &Bl[buf][(128 + wid * 8) * 64]);
        gl_lds16(s + 192 * 64, &Bl[buf][(192 + wid * 8) * 64]);
    };

    f32x4 acc[8][4];
    #pragma unroll
    for (int i = 0; i < 8; ++i)
        #pragma unroll
        for (int j = 0; j < 4; ++j) acc[i][j] = f32x4{0.f, 0.f, 0.f, 0.f};

    const int rA0 = wm * 128 + (lane & 15);
    const int rB0 = wn * 64  + (lane & 15);
    const int xa  = rA0 & 7;
    const int xb  = rB0 & 7;
    const int kb0 = lane >> 4;

    // prologue: stage K-tiles 0 (buf0) and 1 (buf1); wait tile 0 (leave 8 in flight)
    stageB(0, 0); stageA(0, 0);
    stageB(1, 1); stageA(1, 1);
    asm volatile("s_waitcnt vmcnt(8)" ::: "memory");
    asm volatile("s_barrier" ::: "memory");

    f16x8 a[4][2], b[4][2];
    for (int kt = 0; kt < 32; ++kt) {
        const int cur = kt & 1;
        const __half* Ac = &Al[cur][0];
        const __half* Bc = &Bl[cur][0];
        const bool st = kt < 30;

        // ---- P1: 12 ds_read (A mi0-3, B ni0-1); MFMA Q1 ----
        #pragma unroll
        for (int mi = 0; mi < 4; ++mi)
            #pragma unroll
            for (int kk = 0; kk < 2; ++kk)
                a[mi][kk] = *(const f16x8*)&Ac[(rA0 + mi * 16) * 64 + (((kb0 + kk * 4) ^ xa) << 3)];
        #pragma unroll
        for (int ni = 0; ni < 2; ++ni)
            #pragma unroll
            for (int kk = 0; kk < 2; ++kk)
                b[ni][kk] = *(const f16x8*)&Bc[(rB0 + ni * 16) * 64 + (((kb0 + kk * 4) ^ xb) << 3)];
        asm volatile("s_waitcnt lgkmcnt(8)" ::: "memory");
        asm volatile("s_barrier" ::: "memory");
        asm volatile("s_waitcnt lgkmcnt(0)" ::: "memory");
        __builtin_amdgcn_sched_barrier(0);
        __builtin_amdgcn_s_setprio(1);
        #pragma unroll
        for (int mi = 0; mi < 4; ++mi)
            #pragma unroll
            for (int ni = 0; ni < 2; ++ni)
                #pragma unroll
                for (int kk = 0; kk < 2; ++kk)
                    acc[mi][ni] = __builtin_amdgcn_mfma_f32_16x16x32_f16(a[mi][kk], b[ni][kk], acc[mi][ni], 0, 0, 0);
        __builtin_amdgcn_s_setprio(0);
        asm volatile("s_barrier" ::: "memory");

        // ---- P2: 4 ds_read (B ni2-3); MFMA Q2 ----
        #pragma unroll
        for (int ni = 2; ni < 4; ++ni)
            #pragma unroll
            for (int kk = 0; kk < 2; ++kk)
                b[ni][kk] = *(const f16x8*)&Bc[(rB0 + ni * 16) * 64 + (((kb0 + kk * 4) ^ xb) << 3)];
        asm volatile("s_barrier" ::: "memory");
        asm volatile("s_waitcnt lgkmcnt(0)" ::: "memory");
        __builtin_amdgcn_sched_barrier(0);
        __builtin_amdgcn_s_setprio(1);
        #pragma unroll
        for (int mi = 0; mi < 4; ++mi)
            #pragma unroll
            for (int ni = 2; ni < 4; ++ni)
                #pragma unroll
                for (int kk = 0; kk < 2; ++kk)
                    acc[mi][ni] = __builtin_amdgcn_mfma_f32_16x16x32_f16(a[mi][kk], b[ni][kk], acc[mi][ni], 0, 0, 0);
        __builtin_amdgcn_s_setprio(0);
        asm volatile("s_barrier" ::: "memory");

        // ---- P3: 8 ds_read (A mi4-7); stage B(kt+2) [B region consumed]; MFMA Q3 ----
        #pragma unroll
        for (int mi = 0; mi < 4; ++mi)
            #pragma unroll
            for (int kk = 0; kk < 2; ++kk)
                a[mi][kk] = *(const f16x8*)&Ac[(rA0 + (mi + 4) * 16) * 64 + (((kb0 + kk * 4) ^ xa) << 3)];
        if (st) stageB(cur, kt + 2);
        asm volatile("s_barrier" ::: "memory");
        asm volatile("s_waitcnt lgkmcnt(0)" ::: "memory");
        __builtin_amdgcn_sched_barrier(0);
        __builtin_amdgcn_s_setprio(1);
        #pragma unroll
        for (int mi = 0; mi < 4; ++mi)
            #pragma unroll
            for (int ni = 2; ni < 4; ++ni)
                #pragma unroll
                for (int kk = 0; kk < 2; ++kk)
                    acc[mi + 4][ni] = __builtin_amdgcn_mfma_f32_16x16x32_f16(a[mi][kk], b[ni][kk], acc[mi + 4][ni], 0, 0, 0);
        __builtin_amdgcn_s_setprio(0);
        asm volatile("s_barrier" ::: "memory");

        // ---- P4: stage A(kt+2) [A region consumed]; MFMA Q4; vmcnt once ----
        if (st) stageA(cur, kt + 2);
        asm volatile("s_barrier" ::: "memory");
        __builtin_amdgcn_s_setprio(1);
        #pragma unroll
        for (int mi = 0; mi < 4; ++mi)
            #pragma unroll
            for (int ni = 0; ni < 2; ++ni)
                #pragma unroll
                for (int kk = 0; kk < 2; ++kk)
                    acc[mi + 4][ni] = __builtin_amdgcn_mfma_f32_16x16x32_f16(a[mi][kk], b[ni][kk], acc[mi + 4][ni], 0, 0, 0);
        __builtin_amdgcn_s_setprio(0);
        if (st) asm volatile("s_waitcnt vmcnt(8)" ::: "memory");
        else    asm volatile("s_waitcnt vmcnt(0)" ::: "memory");
        asm volatile("s_barrier" ::: "memory");
    }

    // epilogue: silu(gate)*up -> act (ni=2q gate, 2q+1 up; sigma col slot)
    #pragma unroll
    for (int mi = 0; mi < 8; ++mi) {
        #pragma unroll
        for (int q = 0; q < 2; ++q) {
            int gc = ((n0 + wn * 64 + q * 32) >> 5) * 16 + (lane & 15);
            int colstore = (gc & ~7) | (((gc & 3) << 1) | ((gc >> 2) & 1));
            #pragma unroll
            for (int r = 0; r < 4; ++r) {
                int m = m0 + wm * 128 + mi * 16 + (lane >> 4) * 4 + r;
                float gv = acc[mi][2 * q][r];
                float uv = acc[mi][2 * q + 1][r];
                float sig = 1.0f / (1.0f + __expf(-gv));
                act[(size_t)m * IDIM + colstore] = __float2half(gv * sig * uv);
            }
        }
    }
}

// ---------- round-1 fused-decode GEMM1 (fallback if ws too small) ----------
__global__ __launch_bounds__(256, 2) void gemm1_silu(
    const __half* __restrict__ A, const uint32_t* __restrict__ W,
    const float* __restrict__ S, __half* __restrict__ act)
{
    __shared__ __half Alds[BM * BK];
    __shared__ __half Blds[2][BN * BK];
    const int tid  = threadIdx.x;
    const int lane = tid & 63;
    const int wid  = tid >> 6;
    const int wm = wid >> 1, wn = wid & 1;
    const int m0 = blockIdx.y * BM;
    const int c0 = blockIdx.x * BN;

    f32x4 accg[4][4], accu[4][4];
    #pragma unroll
    for (int i = 0; i < 4; ++i)
        #pragma unroll
        for (int j = 0; j < 4; ++j) {
            accg[i][j] = f32x4{0.f, 0.f, 0.f, 0.f};
            accu[i][j] = f32x4{0.f, 0.f, 0.f, 0.f};
        }

    const int c = tid & 127;
    const int rbase = (tid >> 7) * 4;

    for (int kt = 0; kt < HDIM / BK; ++kt) {
        const int k0 = kt * BK;
        #pragma unroll
        for (int i = 0; i < 4; ++i) {
            int u = tid + i * 256;
            int row = u >> 3, kb = u & 7;
            int4 v = *(const int4*)(A + (size_t)(m0 + row) * HDIM + k0 + kb * 8);
            *(int4*)((char*)Alds + row * 128 + ((kb ^ (row & 7)) << 4)) = v;
        }
        const int g = k0 >> 7;
        #pragma unroll
        for (int p = 0; p < 2; ++p) {
            const int ncol = (p ? IDIM : 0) + c0 + c;
            uint32_t s2u = scale_s2u(S[(size_t)g * (2 * IDIM) + ncol]);
            #pragma unroll
            for (int i = 0; i < 4; ++i) {
                int rl = rbase + i;
                uint32_t w = W[(size_t)(kt * 8 + rl) * (2 * IDIM) + ncol];
                int4 d = dec8(w, s2u);
                *(int4*)((char*)&Blds[p][0] + c * 128 + ((rl ^ (c & 7)) << 4)) = d;
            }
        }
        __syncthreads();
        #pragma unroll
        for (int ks = 0; ks < 2; ++ks) {
            f16x8 af[4], bg[4], bu[4];
            const int kb = ks * 4 + (lane >> 4);
            #pragma unroll
            for (int mi = 0; mi < 4; ++mi) {
                int m = wm * 64 + mi * 16 + (lane & 15);
                af[mi] = *(const f16x8*)((const char*)Alds + m * 128 + ((kb ^ (m & 7)) << 4));
            }
            #pragma unroll
            for (int ni = 0; ni < 4; ++ni) {
                int n = wn * 64 + ni * 16 + (lane & 15);
                bg[ni] = *(const f16x8*)((const char*)&Blds[0][0] + n * 128 + ((kb ^ (n & 7)) << 4));
                bu[ni] = *(const f16x8*)((const char*)&Blds[1][0] + n * 128 + ((kb ^ (n & 7)) << 4));
            }
            #pragma unroll
            for (int mi = 0; mi < 4; ++mi)
                #pragma unroll
                for (int ni = 0; ni < 4; ++ni) {
                    accg[mi][ni] = __builtin_amdgcn_mfma_f32_16x16x32_f16(af[mi], bg[ni], accg[mi][ni], 0, 0, 0);
                    accu[mi][ni] = __builtin_amdgcn_mfma_f32_16x16x32_f16(af[mi], bu[ni], accu[mi][ni], 0, 0, 0);
                }
        }
        __syncthreads();
    }
    #pragma unroll
    for (int mi = 0; mi < 4; ++mi) {
        #pragma unroll
        for (int ni = 0; ni < 4; ++ni) {
            int nlog = c0 + wn * 64 + ni * 16 + (lane & 15);
            int ncol = (nlog & ~7) | (((nlog & 3) << 1) | ((nlog >> 2) & 1));
            #pragma unroll
            for (int r = 0; r < 4; ++r) {
                int m = m0 + wm * 64 + mi * 16 + (lane >> 4) * 4 + r;
                float gv = accg[mi][ni][r];
                float uv = accu[mi][ni][r];
                float sig = 1.0f / (1.0f + __expf(-gv));
                act[(size_t)m * IDIM + ncol] = __float2half(gv * sig * uv);
            }
        }
    }
}

// ---------- GEMM2 (unchanged, fused decode): out = moe + act @ deq(Wd) ----------
__global__ __launch_bounds__(256, 2) void gemm2_add(
    const __half* __restrict__ A, const uint32_t* __restrict__ W,
    const float* __restrict__ S, const float* __restrict__ moe,
    float* __restrict__ out)
{
    __shared__ __half Alds[BM * BK];
    __shared__ __half Blds[BN * BK];
    const int tid  = threadIdx.x;
    const int lane = tid & 63;
    const int wid  = tid >> 6;
    const int wm = wid >> 1, wn = wid & 1;
    const int m0 = blockIdx.y * BM;
    const int n0 = blockIdx.x * BN;

    f32x4 acc[4][4];
    #pragma unroll
    for (int i = 0; i < 4; ++i)
        #pragma unroll
        for (int j = 0; j < 4; ++j) acc[i][j] = f32x4{0.f, 0.f, 0.f, 0.f};

    const int c = tid & 127;
    const int rbase = (tid >> 7) * 4;

    for (int kt = 0; kt < IDIM / BK; ++kt) {
        const int k0 = kt * BK;
        #pragma unroll
        for (int i = 0; i < 4; ++i) {
            int u = tid + i * 256;
            int row = u >> 3, kb = u & 7;
            int4 v = *(const int4*)(A + (size_t)(m0 + row) * IDIM + k0 + kb * 8);
            *(int4*)((char*)Alds + row * 128 + ((kb ^ (row & 7)) << 4)) = v;
        }
        {
            const int g = k0 >> 7;
            const int ncol = n0 + c;
            uint32_t s2u = scale_s2u(S[(size_t)g * HDIM + ncol]);
            #pragma unroll
            for (int i = 0; i < 4; ++i) {
                int rl = rbase + i;
                uint32_t w = W[(size_t)(kt * 8 + rl) * HDIM + ncol];
                int4 d = dec8(w, s2u);
                *(int4*)((char*)Blds + c * 128 + ((rl ^ (c & 7)) << 4)) = d;
            }
        }
        __syncthreads();
        #pragma unroll
        for (int ks = 0; ks < 2; ++ks) {
            f16x8 af[4], bf[4];
            const int kb = ks * 4 + (lane >> 4);
            #pragma unroll
            for (int mi = 0; mi < 4; ++mi) {
                int m = wm * 64 + mi * 16 + (lane & 15);
                af[mi] = *(const f16x8*)((const char*)Alds + m * 128 + ((kb ^ (m & 7)) << 4));
            }
            #pragma unroll
            for (int ni = 0; ni < 4; ++ni) {
                int n = wn * 64 + ni * 16 + (lane & 15);
                bf[ni] = *(const f16x8*)((const char*)Blds + n * 128 + ((kb ^ (n & 7)) << 4));
            }
            #pragma unroll
            for (int mi = 0; mi < 4; ++mi)
                #pragma unroll
                for (int ni = 0; ni < 4; ++ni)
                    acc[mi][ni] = __builtin_amdgcn_mfma_f32_16x16x32_f16(af[mi], bf[ni], acc[mi][ni], 0, 0, 0);
        }
        __syncthreads();
    }
    #pragma unroll
    for (int mi = 0; mi < 4; ++mi) {
        #pragma unroll
        for (int ni = 0; ni < 4; ++ni) {
            int n = n0 + wn * 64 + ni * 16 + (lane & 15);
            #pragma unroll
            for (int r = 0; r < 4; ++r) {
                int m = m0 + wm * 64 + mi * 16 + (lane >> 4) * 4 + r;
                out[(size_t)m * HDIM + n] = moe[(size_t)m * HDIM + n] + acc[mi][ni][r];
            }
        }
    }
}

extern "C" void kernel_launch(void* const* d_in, const int* in_sizes, int n_in,
                              void* d_out, int out_size, void* d_ws, size_t ws_size,
                              hipStream_t stream) {
    const float*    hidden = (const float*)d_in[0];
    const float*    moe    = (const float*)d_in[1];
    const uint32_t* wgu    = (const uint32_t*)d_in[2];
    const float*    sgu    = (const float*)d_in[3];
    const uint32_t* wd     = (const uint32_t*)d_in[4];
    const float*    sd     = (const float*)d_in[5];
    float* out = (float*)d_out;

    __half* hidden_f16 = (__half*)d_ws;                                      // 16.78 MB
    __half* act        = (__half*)((char*)d_ws + (size_t)TOKENS * HDIM * 2); // 46.14 MB
    size_t need = (size_t)TOKENS * HDIM * 2 + (size_t)TOKENS * IDIM * 2
                + (size_t)HDIM * (2 * IDIM) * 2;                             // 109 MB

    if (ws_size >= need) {
        __half* wgu16 = (__half*)((char*)d_ws + (size_t)TOKENS * HDIM * 2
                                              + (size_t)TOKENS * IDIM * 2);  // 46.14 MB
        convert_hidden<true><<<dim3(TOKENS * HDIM / 8 / 256), dim3(256), 0, stream>>>(hidden, hidden_f16);
        dequant_wgu<<<dim3(G1_NP / 256, 32), dim3(256), 0, stream>>>(wgu, sgu, wgu16);
        gemm1_8ph<<<dim3(704), dim3(512), 0, stream>>>(hidden_f16, wgu16, act);
    } else {
        convert_hidden<false><<<dim3(TOKENS * HDIM / 8 / 256), dim3(256), 0, stream>>>(hidden, hidden_f16);
        gemm1_silu<<<dim3(IDIM / BN, TOKENS / BM), dim3(256), 0, stream>>>(hidden_f16, wgu, sgu, act);
    }
    gemm2_add<<<dim3(HDIM / BN, TOKENS / BM), dim3(256), 0, stream>>>(act, wd, sd, moe, out);
}

// Round 5
// 328.756 us; speedup vs baseline: 1.4196x; 1.1229x over previous
//
#include <hip/hip_runtime.h>
#include <hip/hip_fp16.h>
#include <stdint.h>

#define TOKENS 4096
#define HDIM   2048
#define IDIM   5632
#define BM 128
#define BN 128
#define BK 64

#define G1_NP  11264
#define G1_KSB (G1_NP * 64)   // halves per K-tile panel of Bt

typedef _Float16 f16x8 __attribute__((ext_vector_type(8)));
typedef float    f32x4 __attribute__((ext_vector_type(4)));

// ---------- fp4 decode helpers (verified rounds 1-4) ----------
__device__ __forceinline__ uint32_t dec2(uint32_t z, uint32_t s2u) {
    uint32_t sgn = (z << 12) & 0x80008000u;
    uint32_t h   = ((z << 9) & 0x0E000E00u) | sgn;
    __half2 hv = __builtin_bit_cast(__half2, h);
    __half2 sv = __builtin_bit_cast(__half2, s2u);
    __half2 r  = __hmul2(hv, sv);
    return __builtin_bit_cast(uint32_t, r);
}
__device__ __forceinline__ int4 dec8(uint32_t w, uint32_t s2u) {
    int4 d;
    d.x = (int)dec2( w        & 0x000F000Fu, s2u);
    d.y = (int)dec2((w >> 4)  & 0x000F000Fu, s2u);
    d.z = (int)dec2((w >> 8)  & 0x000F000Fu, s2u);
    d.w = (int)dec2((w >> 12) & 0x000F000Fu, s2u);
    return d;
}
__device__ __forceinline__ uint32_t scale_s2u(float sc) {
    uint16_t hs = __builtin_bit_cast(uint16_t, __float2half(sc * 16384.0f));
    return (uint32_t)hs * 0x00010001u;
}
__device__ __forceinline__ uint32_t packh(float lo, float hi) {
    __half2 h2 = __halves2half2(__float2half(lo), __float2half(hi));
    return __builtin_bit_cast(uint32_t, h2);
}
__device__ __forceinline__ void gl_lds16(const void* g, void* l) {
    __builtin_amdgcn_global_load_lds(
        (const __attribute__((address_space(1))) uint32_t*)g,
        (__attribute__((address_space(3))) uint32_t*)l, 16, 0, 0);
}

// ---------- hidden fp32 -> f16, sigma k-order within each 8-group ----------
__global__ __launch_bounds__(256) void convert_hidden(
    const float* __restrict__ src, __half* __restrict__ dst)
{
    int idx = blockIdx.x * 256 + threadIdx.x;   // one 8-group per thread
    const float4* s = (const float4*)src + (size_t)idx * 2;
    float4 a = s[0], b = s[1];                  // a = x0..x3, b = x4..x7
    int4 v;
    v.x = (int)packh(a.x, b.x);                 // pos 0,1 = x0,x4
    v.y = (int)packh(a.y, b.y);
    v.z = (int)packh(a.z, b.z);
    v.w = (int)packh(a.w, b.w);
    *((int4*)dst + idx) = v;
}

// ---------- dequant W_gu -> f16 panels Bt[32][11264][64], linear k-word slots,
// sigma-pair values inside each word. One thread per (row np, k-word j):
// wave stores are fully contiguous 1 KB (fixes the round-4 write scatter). ----------
__global__ __launch_bounds__(256) void dequant_wgu(
    const uint32_t* __restrict__ W, const float* __restrict__ S,
    __half* __restrict__ Bt)
{
    int kt = blockIdx.y;                            // 0..31
    int np = blockIdx.x * 32 + (threadIdx.x >> 3);  // interleaved row 0..11263
    int j  = threadIdx.x & 7;                       // logical k-word in tile
    int within = np & 15;
    int pair   = np >> 5;
    int sel    = (np >> 4) & 1;
    int sc = pair * 16 + within + (sel ? IDIM : 0);
    uint32_t s2u = scale_s2u(S[(size_t)(kt >> 1) * (2 * IDIM) + sc]);
    uint32_t w   = W[(size_t)(kt * 8 + j) * (2 * IDIM) + sc];
    int4 d = dec8(w, s2u);
    *(int4*)(Bt + (size_t)kt * G1_KSB + (size_t)np * 64 + j * 8) = d;
}

// ---------- GEMM1: gemm2-twin structure (proven 1050 TF), pure gl_lds staging.
// 128x128 tile, 256 thr, 4 waves (64x64 each), single-buffer 32 KB LDS,
// per-lane source-swizzle (LDS dest linear; src slot s^(row&7)). ----------
__global__ __launch_bounds__(256, 4) void gemm1_s(
    const __half* __restrict__ A, const __half* __restrict__ Bt,
    __half* __restrict__ act)
{
    __shared__ __half Alds[BM * 64];   // 16 KB
    __shared__ __half Blds[BN * 64];   // 16 KB
    const int tid  = threadIdx.x;
    const int lane = tid & 63;
    const int wid  = tid >> 6;
    const int wm = wid >> 1, wn = wid & 1;
    const int m0 = blockIdx.y * BM;
    const int n0 = blockIdx.x * BN;

    f32x4 acc[4][4];
    #pragma unroll
    for (int i = 0; i < 4; ++i)
        #pragma unroll
        for (int j = 0; j < 4; ++j) acc[i][j] = f32x4{0.f, 0.f, 0.f, 0.f};

    // staging descriptors: chunk u = i*256+tid; row=u>>3, s=u&7, src slot s^(row&7)
    const __half* srcA[4];
    const __half* srcB[4];
    #pragma unroll
    for (int i = 0; i < 4; ++i) {
        int u = i * 256 + tid, row = u >> 3, s = u & 7, sl = s ^ (row & 7);
        srcA[i] = A  + (size_t)(m0 + row) * HDIM + sl * 8;
        srcB[i] = Bt + (size_t)(n0 + row) * 64 + sl * 8;
    }

    for (int kt = 0; kt < HDIM / 64; ++kt) {
        #pragma unroll
        for (int i = 0; i < 4; ++i) {
            int u = i * 256 + tid;
            gl_lds16(srcA[i] + (size_t)kt * 64,      (char*)Alds + u * 16);
            gl_lds16(srcB[i] + (size_t)kt * G1_KSB,  (char*)Blds + u * 16);
        }
        __syncthreads();
        #pragma unroll
        for (int ks = 0; ks < 2; ++ks) {
            f16x8 af[4], bf[4];
            const int kb = ks * 4 + (lane >> 4);
            #pragma unroll
            for (int mi = 0; mi < 4; ++mi) {
                int r = wm * 64 + mi * 16 + (lane & 15);
                af[mi] = *(const f16x8*)&Alds[r * 64 + ((kb ^ (r & 7)) << 3)];
            }
            #pragma unroll
            for (int ni = 0; ni < 4; ++ni) {
                int r = wn * 64 + ni * 16 + (lane & 15);
                bf[ni] = *(const f16x8*)&Blds[r * 64 + ((kb ^ (r & 7)) << 3)];
            }
            #pragma unroll
            for (int mi = 0; mi < 4; ++mi)
                #pragma unroll
                for (int ni = 0; ni < 4; ++ni)
                    acc[mi][ni] = __builtin_amdgcn_mfma_f32_16x16x32_f16(af[mi], bf[ni], acc[mi][ni], 0, 0, 0);
        }
        __syncthreads();
    }

    // epilogue: silu(gate)*up -> act (ni=2q gate, 2q+1 up; sigma col slot)
    #pragma unroll
    for (int mi = 0; mi < 4; ++mi) {
        #pragma unroll
        for (int q = 0; q < 2; ++q) {
            int gc = ((n0 + wn * 64 + q * 32) >> 5) * 16 + (lane & 15);
            int colstore = (gc & ~7) | (((gc & 3) << 1) | ((gc >> 2) & 1));
            #pragma unroll
            for (int r = 0; r < 4; ++r) {
                int m = m0 + wm * 64 + mi * 16 + (lane >> 4) * 4 + r;
                float gv = acc[mi][2 * q][r];
                float uv = acc[mi][2 * q + 1][r];
                float sig = 1.0f / (1.0f + __expf(-gv));
                act[(size_t)m * IDIM + colstore] = __float2half(gv * sig * uv);
            }
        }
    }
}

// ---------- round-1 fused-decode GEMM1 (fallback if ws too small) ----------
__global__ __launch_bounds__(256, 2) void gemm1_silu(
    const __half* __restrict__ A, const uint32_t* __restrict__ W,
    const float* __restrict__ S, __half* __restrict__ act)
{
    __shared__ __half Alds[BM * BK];
    __shared__ __half Blds[2][BN * BK];
    const int tid  = threadIdx.x;
    const int lane = tid & 63;
    const int wid  = tid >> 6;
    const int wm = wid >> 1, wn = wid & 1;
    const int m0 = blockIdx.y * BM;
    const int c0 = blockIdx.x * BN;

    f32x4 accg[4][4], accu[4][4];
    #pragma unroll
    for (int i = 0; i < 4; ++i)
        #pragma unroll
        for (int j = 0; j < 4; ++j) {
            accg[i][j] = f32x4{0.f, 0.f, 0.f, 0.f};
            accu[i][j] = f32x4{0.f, 0.f, 0.f, 0.f};
        }

    const int c = tid & 127;
    const int rbase = (tid >> 7) * 4;

    for (int kt = 0; kt < HDIM / BK; ++kt) {
        const int k0 = kt * BK;
        #pragma unroll
        for (int i = 0; i < 4; ++i) {
            int u = tid + i * 256;
            int row = u >> 3, kb = u & 7;
            int4 v = *(const int4*)(A + (size_t)(m0 + row) * HDIM + k0 + kb * 8);
            *(int4*)((char*)Alds + row * 128 + ((kb ^ (row & 7)) << 4)) = v;
        }
        const int g = k0 >> 7;
        #pragma unroll
        for (int p = 0; p < 2; ++p) {
            const int ncol = (p ? IDIM : 0) + c0 + c;
            uint32_t s2u = scale_s2u(S[(size_t)g * (2 * IDIM) + ncol]);
            #pragma unroll
            for (int i = 0; i < 4; ++i) {
                int rl = rbase + i;
                uint32_t w = W[(size_t)(kt * 8 + rl) * (2 * IDIM) + ncol];
                int4 d = dec8(w, s2u);
                *(int4*)((char*)&Blds[p][0] + c * 128 + ((rl ^ (c & 7)) << 4)) = d;
            }
        }
        __syncthreads();
        #pragma unroll
        for (int ks = 0; ks < 2; ++ks) {
            f16x8 af[4], bg[4], bu[4];
            const int kb = ks * 4 + (lane >> 4);
            #pragma unroll
            for (int mi = 0; mi < 4; ++mi) {
                int m = wm * 64 + mi * 16 + (lane & 15);
                af[mi] = *(const f16x8*)((const char*)Alds + m * 128 + ((kb ^ (m & 7)) << 4));
            }
            #pragma unroll
            for (int ni = 0; ni < 4; ++ni) {
                int n = wn * 64 + ni * 16 + (lane & 15);
                bg[ni] = *(const f16x8*)((const char*)&Blds[0][0] + n * 128 + ((kb ^ (n & 7)) << 4));
                bu[ni] = *(const f16x8*)((const char*)&Blds[1][0] + n * 128 + ((kb ^ (n & 7)) << 4));
            }
            #pragma unroll
            for (int mi = 0; mi < 4; ++mi)
                #pragma unroll
                for (int ni = 0; ni < 4; ++ni) {
                    accg[mi][ni] = __builtin_amdgcn_mfma_f32_16x16x32_f16(af[mi], bg[ni], accg[mi][ni], 0, 0, 0);
                    accu[mi][ni] = __builtin_amdgcn_mfma_f32_16x16x32_f16(af[mi], bu[ni], accu[mi][ni], 0, 0, 0);
                }
        }
        __syncthreads();
    }
    #pragma unroll
    for (int mi = 0; mi < 4; ++mi) {
        #pragma unroll
        for (int ni = 0; ni < 4; ++ni) {
            int nlog = c0 + wn * 64 + ni * 16 + (lane & 15);
            int ncol = (nlog & ~7) | (((nlog & 3) << 1) | ((nlog >> 2) & 1));
            #pragma unroll
            for (int r = 0; r < 4; ++r) {
                int m = m0 + wm * 64 + mi * 16 + (lane >> 4) * 4 + r;
                float gv = accg[mi][ni][r];
                float uv = accu[mi][ni][r];
                float sig = 1.0f / (1.0f + __expf(-gv));
                act[(size_t)m * IDIM + ncol] = __float2half(gv * sig * uv);
            }
        }
    }
}

// ---------- GEMM2 (unchanged, fused decode): out = moe + act @ deq(Wd) ----------
__global__ __launch_bounds__(256, 2) void gemm2_add(
    const __half* __restrict__ A, const uint32_t* __restrict__ W,
    const float* __restrict__ S, const float* __restrict__ moe,
    float* __restrict__ out)
{
    __shared__ __half Alds[BM * BK];
    __shared__ __half Blds[BN * BK];
    const int tid  = threadIdx.x;
    const int lane = tid & 63;
    const int wid  = tid >> 6;
    const int wm = wid >> 1, wn = wid & 1;
    const int m0 = blockIdx.y * BM;
    const int n0 = blockIdx.x * BN;

    f32x4 acc[4][4];
    #pragma unroll
    for (int i = 0; i < 4; ++i)
        #pragma unroll
        for (int j = 0; j < 4; ++j) acc[i][j] = f32x4{0.f, 0.f, 0.f, 0.f};

    const int c = tid & 127;
    const int rbase = (tid >> 7) * 4;

    for (int kt = 0; kt < IDIM / BK; ++kt) {
        const int k0 = kt * BK;
        #pragma unroll
        for (int i = 0; i < 4; ++i) {
            int u = tid + i * 256;
            int row = u >> 3, kb = u & 7;
            int4 v = *(const int4*)(A + (size_t)(m0 + row) * IDIM + k0 + kb * 8);
            *(int4*)((char*)Alds + row * 128 + ((kb ^ (row & 7)) << 4)) = v;
        }
        {
            const int g = k0 >> 7;
            const int ncol = n0 + c;
            uint32_t s2u = scale_s2u(S[(size_t)g * HDIM + ncol]);
            #pragma unroll
            for (int i = 0; i < 4; ++i) {
                int rl = rbase + i;
                uint32_t w = W[(size_t)(kt * 8 + rl) * HDIM + ncol];
                int4 d = dec8(w, s2u);
                *(int4*)((char*)Blds + c * 128 + ((rl ^ (c & 7)) << 4)) = d;
            }
        }
        __syncthreads();
        #pragma unroll
        for (int ks = 0; ks < 2; ++ks) {
            f16x8 af[4], bf[4];
            const int kb = ks * 4 + (lane >> 4);
            #pragma unroll
            for (int mi = 0; mi < 4; ++mi) {
                int m = wm * 64 + mi * 16 + (lane & 15);
                af[mi] = *(const f16x8*)((const char*)Alds + m * 128 + ((kb ^ (m & 7)) << 4));
            }
            #pragma unroll
            for (int ni = 0; ni < 4; ++ni) {
                int n = wn * 64 + ni * 16 + (lane & 15);
                bf[ni] = *(const f16x8*)((const char*)Blds + n * 128 + ((kb ^ (n & 7)) << 4));
            }
            #pragma unroll
            for (int mi = 0; mi < 4; ++mi)
                #pragma unroll
                for (int ni = 0; ni < 4; ++ni)
                    acc[mi][ni] = __builtin_amdgcn_mfma_f32_16x16x32_f16(af[mi], bf[ni], acc[mi][ni], 0, 0, 0);
        }
        __syncthreads();
    }
    #pragma unroll
    for (int mi = 0; mi < 4; ++mi) {
        #pragma unroll
        for (int ni = 0; ni < 4; ++ni) {
            int n = n0 + wn * 64 + ni * 16 + (lane & 15);
            #pragma unroll
            for (int r = 0; r < 4; ++r) {
                int m = m0 + wm * 64 + mi * 16 + (lane >> 4) * 4 + r;
                out[(size_t)m * HDIM + n] = moe[(size_t)m * HDIM + n] + acc[mi][ni][r];
            }
        }
    }
}

extern "C" void kernel_launch(void* const* d_in, const int* in_sizes, int n_in,
                              void* d_out, int out_size, void* d_ws, size_t ws_size,
                              hipStream_t stream) {
    const float*    hidden = (const float*)d_in[0];
    const float*    moe    = (const float*)d_in[1];
    const uint32_t* wgu    = (const uint32_t*)d_in[2];
    const float*    sgu    = (const float*)d_in[3];
    const uint32_t* wd     = (const uint32_t*)d_in[4];
    const float*    sd     = (const float*)d_in[5];
    float* out = (float*)d_out;

    __half* hidden_f16 = (__half*)d_ws;                                      // 16.78 MB
    __half* act        = (__half*)((char*)d_ws + (size_t)TOKENS * HDIM * 2); // 46.14 MB
    size_t need = (size_t)TOKENS * HDIM * 2 + (size_t)TOKENS * IDIM * 2
                + (size_t)HDIM * (2 * IDIM) * 2;                             // 109 MB

    convert_hidden<<<dim3(TOKENS * HDIM / 8 / 256), dim3(256), 0, stream>>>(hidden, hidden_f16);
    if (ws_size >= need) {
        __half* wgu16 = (__half*)((char*)d_ws + (size_t)TOKENS * HDIM * 2
                                              + (size_t)TOKENS * IDIM * 2);  // 46.14 MB
        dequant_wgu<<<dim3(G1_NP / 32, 32), dim3(256), 0, stream>>>(wgu, sgu, wgu16);
        gemm1_s<<<dim3(IDIM * 2 / BN, TOKENS / BM), dim3(256), 0, stream>>>(hidden_f16, wgu16, act);
    } else {
        gemm1_silu<<<dim3(IDIM / BN, TOKENS / BM), dim3(256), 0, stream>>>(hidden_f16, wgu, sgu, act);
    }
    gemm2_add<<<dim3(HDIM / BN, TOKENS / BM), dim3(256), 0, stream>>>(act, wd, sd, moe, out);
}

// Round 6
// 324.261 us; speedup vs baseline: 1.4393x; 1.0139x over previous
//
#include <hip/hip_runtime.h>
#include <hip/hip_fp16.h>
#include <stdint.h>

#define TOKENS 4096
#define HDIM   2048
#define IDIM   5632
#define BM 128
#define BN 128
#define BK 64

#define G1_NP  11264
#define G1_KSB (G1_NP * 64)    // halves per K-tile panel of Bt (gate/up)
#define G2_KSB (HDIM * 64)     // halves per K-tile panel of Btd (down)

typedef _Float16 f16x8 __attribute__((ext_vector_type(8)));
typedef float    f32x4 __attribute__((ext_vector_type(4)));

// ---------- fp4 decode helpers (verified rounds 1-5) ----------
__device__ __forceinline__ uint32_t dec2(uint32_t z, uint32_t s2u) {
    uint32_t sgn = (z << 12) & 0x80008000u;
    uint32_t h   = ((z << 9) & 0x0E000E00u) | sgn;
    __half2 hv = __builtin_bit_cast(__half2, h);
    __half2 sv = __builtin_bit_cast(__half2, s2u);
    __half2 r  = __hmul2(hv, sv);
    return __builtin_bit_cast(uint32_t, r);
}
__device__ __forceinline__ int4 dec8(uint32_t w, uint32_t s2u) {
    int4 d;
    d.x = (int)dec2( w        & 0x000F000Fu, s2u);
    d.y = (int)dec2((w >> 4)  & 0x000F000Fu, s2u);
    d.z = (int)dec2((w >> 8)  & 0x000F000Fu, s2u);
    d.w = (int)dec2((w >> 12) & 0x000F000Fu, s2u);
    return d;
}
__device__ __forceinline__ uint32_t scale_s2u(float sc) {
    uint16_t hs = __builtin_bit_cast(uint16_t, __float2half(sc * 16384.0f));
    return (uint32_t)hs * 0x00010001u;
}
__device__ __forceinline__ uint32_t packh(float lo, float hi) {
    __half2 h2 = __halves2half2(__float2half(lo), __float2half(hi));
    return __builtin_bit_cast(uint32_t, h2);
}
__device__ __forceinline__ void gl_lds16(const void* g, void* l) {
    __builtin_amdgcn_global_load_lds(
        (const __attribute__((address_space(1))) uint32_t*)g,
        (__attribute__((address_space(3))) uint32_t*)l, 16, 0, 0);
}

// ---------- hidden fp32 -> f16, sigma k-order within each 8-group ----------
__global__ __launch_bounds__(256) void convert_hidden(
    const float* __restrict__ src, __half* __restrict__ dst)
{
    int idx = blockIdx.x * 256 + threadIdx.x;   // one 8-group per thread
    const float4* s = (const float4*)src + (size_t)idx * 2;
    float4 a = s[0], b = s[1];                  // a = x0..x3, b = x4..x7
    int4 v;
    v.x = (int)packh(a.x, b.x);                 // pos 0,1 = x0,x4
    v.y = (int)packh(a.y, b.y);
    v.z = (int)packh(a.z, b.z);
    v.w = (int)packh(a.w, b.w);
    *((int4*)dst + idx) = v;
}

// ---------- dequant W_gu -> f16 panels Bt[32][11264][64] (gate/up 16-col
// interleave, sigma k-order inside each word). v4: thread<->column, j-loop:
// reads coalesced (1 KB/wave/iter), writes 128 B contiguous per thread. ----------
__global__ __launch_bounds__(256) void dequant_wgu(
    const uint32_t* __restrict__ W, const float* __restrict__ S,
    __half* __restrict__ Bt)
{
    int kt = blockIdx.y;                            // 0..31
    int np = blockIdx.x * 256 + threadIdx.x;        // interleaved row 0..11263
    int sc = (np >> 5) * 16 + (np & 15) + (((np >> 4) & 1) ? IDIM : 0);
    uint32_t s2u = scale_s2u(S[(size_t)(kt >> 1) * (2 * IDIM) + sc]);
    __half* dst = Bt + (size_t)kt * G1_KSB + (size_t)np * 64;
    #pragma unroll
    for (int j = 0; j < 8; ++j) {
        uint32_t w = W[(size_t)(kt * 8 + j) * (2 * IDIM) + sc];
        int4 d = dec8(w, s2u);
        *(int4*)(dst + j * 8) = d;
    }
}

// ---------- dequant W_d -> f16 panels Btd[88][2048][64], same pattern ----------
__global__ __launch_bounds__(256) void dequant_wd(
    const uint32_t* __restrict__ W, const float* __restrict__ S,
    __half* __restrict__ Bt)
{
    int kt = blockIdx.y;                            // 0..87
    int n  = blockIdx.x * 256 + threadIdx.x;        // output col 0..2047
    uint32_t s2u = scale_s2u(S[(size_t)(kt >> 1) * HDIM + n]);
    __half* dst = Bt + (size_t)kt * G2_KSB + (size_t)n * 64;
    #pragma unroll
    for (int j = 0; j < 8; ++j) {
        uint32_t w = W[(size_t)(kt * 8 + j) * HDIM + n];
        int4 d = dec8(w, s2u);
        *(int4*)(dst + j * 8) = d;
    }
}

// ---------- GEMM1: proven structure (r5: 1080 TF). 128x128 tile, 256 thr,
// 4 waves (64x64 each), single-buffer 32 KB LDS, pure gl_lds staging with
// per-lane source-swizzle (LDS dest linear; src slot s^(row&7)). ----------
__global__ __launch_bounds__(256, 4) void gemm1_s(
    const __half* __restrict__ A, const __half* __restrict__ Bt,
    __half* __restrict__ act)
{
    __shared__ __half Alds[BM * 64];   // 16 KB
    __shared__ __half Blds[BN * 64];   // 16 KB
    const int tid  = threadIdx.x;
    const int lane = tid & 63;
    const int wid  = tid >> 6;
    const int wm = wid >> 1, wn = wid & 1;
    const int m0 = blockIdx.y * BM;
    const int n0 = blockIdx.x * BN;

    f32x4 acc[4][4];
    #pragma unroll
    for (int i = 0; i < 4; ++i)
        #pragma unroll
        for (int j = 0; j < 4; ++j) acc[i][j] = f32x4{0.f, 0.f, 0.f, 0.f};

    const __half* srcA[4];
    const __half* srcB[4];
    #pragma unroll
    for (int i = 0; i < 4; ++i) {
        int u = i * 256 + tid, row = u >> 3, s = u & 7, sl = s ^ (row & 7);
        srcA[i] = A  + (size_t)(m0 + row) * HDIM + sl * 8;
        srcB[i] = Bt + (size_t)(n0 + row) * 64 + sl * 8;
    }

    for (int kt = 0; kt < HDIM / 64; ++kt) {
        #pragma unroll
        for (int i = 0; i < 4; ++i) {
            int u = i * 256 + tid;
            gl_lds16(srcA[i] + (size_t)kt * 64,      (char*)Alds + u * 16);
            gl_lds16(srcB[i] + (size_t)kt * G1_KSB,  (char*)Blds + u * 16);
        }
        __syncthreads();
        #pragma unroll
        for (int ks = 0; ks < 2; ++ks) {
            f16x8 af[4], bf[4];
            const int kb = ks * 4 + (lane >> 4);
            #pragma unroll
            for (int mi = 0; mi < 4; ++mi) {
                int r = wm * 64 + mi * 16 + (lane & 15);
                af[mi] = *(const f16x8*)&Alds[r * 64 + ((kb ^ (r & 7)) << 3)];
            }
            #pragma unroll
            for (int ni = 0; ni < 4; ++ni) {
                int r = wn * 64 + ni * 16 + (lane & 15);
                bf[ni] = *(const f16x8*)&Blds[r * 64 + ((kb ^ (r & 7)) << 3)];
            }
            #pragma unroll
            for (int mi = 0; mi < 4; ++mi)
                #pragma unroll
                for (int ni = 0; ni < 4; ++ni)
                    acc[mi][ni] = __builtin_amdgcn_mfma_f32_16x16x32_f16(af[mi], bf[ni], acc[mi][ni], 0, 0, 0);
        }
        __syncthreads();
    }

    // epilogue: silu(gate)*up -> act (ni=2q gate, 2q+1 up; sigma col slot)
    #pragma unroll
    for (int mi = 0; mi < 4; ++mi) {
        #pragma unroll
        for (int q = 0; q < 2; ++q) {
            int gc = ((n0 + wn * 64 + q * 32) >> 5) * 16 + (lane & 15);
            int colstore = (gc & ~7) | (((gc & 3) << 1) | ((gc >> 2) & 1));
            #pragma unroll
            for (int r = 0; r < 4; ++r) {
                int m = m0 + wm * 64 + mi * 16 + (lane >> 4) * 4 + r;
                float gv = acc[mi][2 * q][r];
                float uv = acc[mi][2 * q + 1][r];
                float sig = 1.0f / (1.0f + __expf(-gv));
                act[(size_t)m * IDIM + colstore] = __float2half(gv * sig * uv);
            }
        }
    }
}

// ---------- GEMM2: twin of gemm1_s; pre-dequant B, moe-add epilogue ----------
__global__ __launch_bounds__(256, 4) void gemm2_s(
    const __half* __restrict__ A, const __half* __restrict__ Bt,
    const float* __restrict__ moe, float* __restrict__ out)
{
    __shared__ __half Alds[BM * 64];   // 16 KB
    __shared__ __half Blds[BN * 64];   // 16 KB
    const int tid  = threadIdx.x;
    const int lane = tid & 63;
    const int wid  = tid >> 6;
    const int wm = wid >> 1, wn = wid & 1;
    const int m0 = blockIdx.y * BM;
    const int n0 = blockIdx.x * BN;

    f32x4 acc[4][4];
    #pragma unroll
    for (int i = 0; i < 4; ++i)
        #pragma unroll
        for (int j = 0; j < 4; ++j) acc[i][j] = f32x4{0.f, 0.f, 0.f, 0.f};

    const __half* srcA[4];
    const __half* srcB[4];
    #pragma unroll
    for (int i = 0; i < 4; ++i) {
        int u = i * 256 + tid, row = u >> 3, s = u & 7, sl = s ^ (row & 7);
        srcA[i] = A  + (size_t)(m0 + row) * IDIM + sl * 8;
        srcB[i] = Bt + (size_t)(n0 + row) * 64 + sl * 8;
    }

    for (int kt = 0; kt < IDIM / 64; ++kt) {
        #pragma unroll
        for (int i = 0; i < 4; ++i) {
            int u = i * 256 + tid;
            gl_lds16(srcA[i] + (size_t)kt * 64,      (char*)Alds + u * 16);
            gl_lds16(srcB[i] + (size_t)kt * G2_KSB,  (char*)Blds + u * 16);
        }
        __syncthreads();
        #pragma unroll
        for (int ks = 0; ks < 2; ++ks) {
            f16x8 af[4], bf[4];
            const int kb = ks * 4 + (lane >> 4);
            #pragma unroll
            for (int mi = 0; mi < 4; ++mi) {
                int r = wm * 64 + mi * 16 + (lane & 15);
                af[mi] = *(const f16x8*)&Alds[r * 64 + ((kb ^ (r & 7)) << 3)];
            }
            #pragma unroll
            for (int ni = 0; ni < 4; ++ni) {
                int r = wn * 64 + ni * 16 + (lane & 15);
                bf[ni] = *(const f16x8*)&Blds[r * 64 + ((kb ^ (r & 7)) << 3)];
            }
            #pragma unroll
            for (int mi = 0; mi < 4; ++mi)
                #pragma unroll
                for (int ni = 0; ni < 4; ++ni)
                    acc[mi][ni] = __builtin_amdgcn_mfma_f32_16x16x32_f16(af[mi], bf[ni], acc[mi][ni], 0, 0, 0);
        }
        __syncthreads();
    }
    #pragma unroll
    for (int mi = 0; mi < 4; ++mi) {
        #pragma unroll
        for (int ni = 0; ni < 4; ++ni) {
            int n = n0 + wn * 64 + ni * 16 + (lane & 15);
            #pragma unroll
            for (int r = 0; r < 4; ++r) {
                int m = m0 + wm * 64 + mi * 16 + (lane >> 4) * 4 + r;
                out[(size_t)m * HDIM + n] = moe[(size_t)m * HDIM + n] + acc[mi][ni][r];
            }
        }
    }
}

// ---------- round-1 fused-decode GEMM1 (fallback if ws too small) ----------
__global__ __launch_bounds__(256, 2) void gemm1_silu(
    const __half* __restrict__ A, const uint32_t* __restrict__ W,
    const float* __restrict__ S, __half* __restrict__ act)
{
    __shared__ __half Alds[BM * BK];
    __shared__ __half Blds[2][BN * BK];
    const int tid  = threadIdx.x;
    const int lane = tid & 63;
    const int wid  = tid >> 6;
    const int wm = wid >> 1, wn = wid & 1;
    const int m0 = blockIdx.y * BM;
    const int c0 = blockIdx.x * BN;

    f32x4 accg[4][4], accu[4][4];
    #pragma unroll
    for (int i = 0; i < 4; ++i)
        #pragma unroll
        for (int j = 0; j < 4; ++j) {
            accg[i][j] = f32x4{0.f, 0.f, 0.f, 0.f};
            accu[i][j] = f32x4{0.f, 0.f, 0.f, 0.f};
        }

    const int c = tid & 127;
    const int rbase = (tid >> 7) * 4;

    for (int kt = 0; kt < HDIM / BK; ++kt) {
        const int k0 = kt * BK;
        #pragma unroll
        for (int i = 0; i < 4; ++i) {
            int u = tid + i * 256;
            int row = u >> 3, kb = u & 7;
            int4 v = *(const int4*)(A + (size_t)(m0 + row) * HDIM + k0 + kb * 8);
            *(int4*)((char*)Alds + row * 128 + ((kb ^ (row & 7)) << 4)) = v;
        }
        const int g = k0 >> 7;
        #pragma unroll
        for (int p = 0; p < 2; ++p) {
            const int ncol = (p ? IDIM : 0) + c0 + c;
            uint32_t s2u = scale_s2u(S[(size_t)g * (2 * IDIM) + ncol]);
            #pragma unroll
            for (int i = 0; i < 4; ++i) {
                int rl = rbase + i;
                uint32_t w = W[(size_t)(kt * 8 + rl) * (2 * IDIM) + ncol];
                int4 d = dec8(w, s2u);
                *(int4*)((char*)&Blds[p][0] + c * 128 + ((rl ^ (c & 7)) << 4)) = d;
            }
        }
        __syncthreads();
        #pragma unroll
        for (int ks = 0; ks < 2; ++ks) {
            f16x8 af[4], bg[4], bu[4];
            const int kb = ks * 4 + (lane >> 4);
            #pragma unroll
            for (int mi = 0; mi < 4; ++mi) {
                int m = wm * 64 + mi * 16 + (lane & 15);
                af[mi] = *(const f16x8*)((const char*)Alds + m * 128 + ((kb ^ (m & 7)) << 4));
            }
            #pragma unroll
            for (int ni = 0; ni < 4; ++ni) {
                int n = wn * 64 + ni * 16 + (lane & 15);
                bg[ni] = *(const f16x8*)((const char*)&Blds[0][0] + n * 128 + ((kb ^ (n & 7)) << 4));
                bu[ni] = *(const f16x8*)((const char*)&Blds[1][0] + n * 128 + ((kb ^ (n & 7)) << 4));
            }
            #pragma unroll
            for (int mi = 0; mi < 4; ++mi)
                #pragma unroll
                for (int ni = 0; ni < 4; ++ni) {
                    accg[mi][ni] = __builtin_amdgcn_mfma_f32_16x16x32_f16(af[mi], bg[ni], accg[mi][ni], 0, 0, 0);
                    accu[mi][ni] = __builtin_amdgcn_mfma_f32_16x16x32_f16(af[mi], bu[ni], accu[mi][ni], 0, 0, 0);
                }
        }
        __syncthreads();
    }
    #pragma unroll
    for (int mi = 0; mi < 4; ++mi) {
        #pragma unroll
        for (int ni = 0; ni < 4; ++ni) {
            int nlog = c0 + wn * 64 + ni * 16 + (lane & 15);
            int ncol = (nlog & ~7) | (((nlog & 3) << 1) | ((nlog >> 2) & 1));
            #pragma unroll
            for (int r = 0; r < 4; ++r) {
                int m = m0 + wm * 64 + mi * 16 + (lane >> 4) * 4 + r;
                float gv = accg[mi][ni][r];
                float uv = accu[mi][ni][r];
                float sig = 1.0f / (1.0f + __expf(-gv));
                act[(size_t)m * IDIM + ncol] = __float2half(gv * sig * uv);
            }
        }
    }
}

// ---------- fused-decode GEMM2 (fallback if ws too small) ----------
__global__ __launch_bounds__(256, 2) void gemm2_add(
    const __half* __restrict__ A, const uint32_t* __restrict__ W,
    const float* __restrict__ S, const float* __restrict__ moe,
    float* __restrict__ out)
{
    __shared__ __half Alds[BM * BK];
    __shared__ __half Blds[BN * BK];
    const int tid  = threadIdx.x;
    const int lane = tid & 63;
    const int wid  = tid >> 6;
    const int wm = wid >> 1, wn = wid & 1;
    const int m0 = blockIdx.y * BM;
    const int n0 = blockIdx.x * BN;

    f32x4 acc[4][4];
    #pragma unroll
    for (int i = 0; i < 4; ++i)
        #pragma unroll
        for (int j = 0; j < 4; ++j) acc[i][j] = f32x4{0.f, 0.f, 0.f, 0.f};

    const int c = tid & 127;
    const int rbase = (tid >> 7) * 4;

    for (int kt = 0; kt < IDIM / BK; ++kt) {
        const int k0 = kt * BK;
        #pragma unroll
        for (int i = 0; i < 4; ++i) {
            int u = tid + i * 256;
            int row = u >> 3, kb = u & 7;
            int4 v = *(const int4*)(A + (size_t)(m0 + row) * IDIM + k0 + kb * 8);
            *(int4*)((char*)Alds + row * 128 + ((kb ^ (row & 7)) << 4)) = v;
        }
        {
            const int g = k0 >> 7;
            const int ncol = n0 + c;
            uint32_t s2u = scale_s2u(S[(size_t)g * HDIM + ncol]);
            #pragma unroll
            for (int i = 0; i < 4; ++i) {
                int rl = rbase + i;
                uint32_t w = W[(size_t)(kt * 8 + rl) * HDIM + ncol];
                int4 d = dec8(w, s2u);
                *(int4*)((char*)Blds + c * 128 + ((rl ^ (c & 7)) << 4)) = d;
            }
        }
        __syncthreads();
        #pragma unroll
        for (int ks = 0; ks < 2; ++ks) {
            f16x8 af[4], bf[4];
            const int kb = ks * 4 + (lane >> 4);
            #pragma unroll
            for (int mi = 0; mi < 4; ++mi) {
                int m = wm * 64 + mi * 16 + (lane & 15);
                af[mi] = *(const f16x8*)((const char*)Alds + m * 128 + ((kb ^ (m & 7)) << 4));
            }
            #pragma unroll
            for (int ni = 0; ni < 4; ++ni) {
                int n = wn * 64 + ni * 16 + (lane & 15);
                bf[ni] = *(const f16x8*)((const char*)Blds + n * 128 + ((kb ^ (n & 7)) << 4));
            }
            #pragma unroll
            for (int mi = 0; mi < 4; ++mi)
                #pragma unroll
                for (int ni = 0; ni < 4; ++ni)
                    acc[mi][ni] = __builtin_amdgcn_mfma_f32_16x16x32_f16(af[mi], bf[ni], acc[mi][ni], 0, 0, 0);
        }
        __syncthreads();
    }
    #pragma unroll
    for (int mi = 0; mi < 4; ++mi) {
        #pragma unroll
        for (int ni = 0; ni < 4; ++ni) {
            int n = n0 + wn * 64 + ni * 16 + (lane & 15);
            #pragma unroll
            for (int r = 0; r < 4; ++r) {
                int m = m0 + wm * 64 + mi * 16 + (lane >> 4) * 4 + r;
                out[(size_t)m * HDIM + n] = moe[(size_t)m * HDIM + n] + acc[mi][ni][r];
            }
        }
    }
}

extern "C" void kernel_launch(void* const* d_in, const int* in_sizes, int n_in,
                              void* d_out, int out_size, void* d_ws, size_t ws_size,
                              hipStream_t stream) {
    const float*    hidden = (const float*)d_in[0];
    const float*    moe    = (const float*)d_in[1];
    const uint32_t* wgu    = (const uint32_t*)d_in[2];
    const float*    sgu    = (const float*)d_in[3];
    const uint32_t* wd     = (const uint32_t*)d_in[4];
    const float*    sd     = (const float*)d_in[5];
    float* out = (float*)d_out;

    const size_t sz_hidden = (size_t)TOKENS * HDIM * 2;      // 16.78 MB
    const size_t sz_act    = (size_t)TOKENS * IDIM * 2;      // 46.14 MB
    const size_t sz_wgu16  = (size_t)HDIM * 2 * IDIM * 2;    // 46.14 MB
    const size_t sz_wd16   = (size_t)IDIM * HDIM * 2;        // 23.07 MB

    __half* hidden_f16 = (__half*)d_ws;
    __half* act        = (__half*)((char*)d_ws + sz_hidden);
    __half* wgu16      = (__half*)((char*)d_ws + sz_hidden + sz_act);
    __half* wd16       = (__half*)((char*)d_ws + sz_hidden + sz_act + sz_wgu16);

    const size_t need_g1 = sz_hidden + sz_act + sz_wgu16;            // 109 MB
    const size_t need_g2 = need_g1 + sz_wd16;                        // 132 MB

    convert_hidden<<<dim3(TOKENS * HDIM / 8 / 256), dim3(256), 0, stream>>>(hidden, hidden_f16);

    if (ws_size >= need_g1) {
        dequant_wgu<<<dim3(G1_NP / 256, 32), dim3(256), 0, stream>>>(wgu, sgu, wgu16);
        gemm1_s<<<dim3(IDIM * 2 / BN, TOKENS / BM), dim3(256), 0, stream>>>(hidden_f16, wgu16, act);
    } else {
        gemm1_silu<<<dim3(IDIM / BN, TOKENS / BM), dim3(256), 0, stream>>>(hidden_f16, wgu, sgu, act);
    }

    if (ws_size >= need_g2) {
        dequant_wd<<<dim3(HDIM / 256, IDIM / 64), dim3(256), 0, stream>>>(wd, sd, wd16);
        gemm2_s<<<dim3(HDIM / BN, TOKENS / BM), dim3(256), 0, stream>>>(act, wd16, moe, out);
    } else {
        gemm2_add<<<dim3(HDIM / BN, TOKENS / BM), dim3(256), 0, stream>>>(act, wd, sd, moe, out);
    }
}

// Round 7
// 323.093 us; speedup vs baseline: 1.4445x; 1.0036x over previous
//
#include <hip/hip_runtime.h>
#include <hip/hip_fp16.h>
#include <stdint.h>

#define TOKENS 4096
#define HDIM   2048
#define IDIM   5632
#define BM 128
#define BN 128
#define BK 64

#define G1_NP  11264
#define G1_KSB (G1_NP * 64)    // halves per K-tile panel of Bt (gate/up)

typedef _Float16 f16x8 __attribute__((ext_vector_type(8)));
typedef float    f32x4 __attribute__((ext_vector_type(4)));

// ---------- fp4 decode helpers (verified rounds 1-6) ----------
__device__ __forceinline__ uint32_t dec2(uint32_t z, uint32_t s2u) {
    uint32_t sgn = (z << 12) & 0x80008000u;
    uint32_t h   = ((z << 9) & 0x0E000E00u) | sgn;
    __half2 hv = __builtin_bit_cast(__half2, h);
    __half2 sv = __builtin_bit_cast(__half2, s2u);
    __half2 r  = __hmul2(hv, sv);
    return __builtin_bit_cast(uint32_t, r);
}
__device__ __forceinline__ int4 dec8(uint32_t w, uint32_t s2u) {
    int4 d;
    d.x = (int)dec2( w        & 0x000F000Fu, s2u);
    d.y = (int)dec2((w >> 4)  & 0x000F000Fu, s2u);
    d.z = (int)dec2((w >> 8)  & 0x000F000Fu, s2u);
    d.w = (int)dec2((w >> 12) & 0x000F000Fu, s2u);
    return d;
}
__device__ __forceinline__ uint32_t scale_s2u(float sc) {
    uint16_t hs = __builtin_bit_cast(uint16_t, __float2half(sc * 16384.0f));
    return (uint32_t)hs * 0x00010001u;
}
__device__ __forceinline__ uint32_t packh(float lo, float hi) {
    __half2 h2 = __halves2half2(__float2half(lo), __float2half(hi));
    return __builtin_bit_cast(uint32_t, h2);
}
__device__ __forceinline__ void gl_lds16(const void* g, void* l) {
    __builtin_amdgcn_global_load_lds(
        (const __attribute__((address_space(1))) uint32_t*)g,
        (__attribute__((address_space(3))) uint32_t*)l, 16, 0, 0);
}

// ---------- hidden fp32 -> f16, sigma k-order within each 8-group ----------
__global__ __launch_bounds__(256) void convert_hidden(
    const float* __restrict__ src, __half* __restrict__ dst)
{
    int idx = blockIdx.x * 256 + threadIdx.x;   // one 8-group per thread
    const float4* s = (const float4*)src + (size_t)idx * 2;
    float4 a = s[0], b = s[1];                  // a = x0..x3, b = x4..x7
    int4 v;
    v.x = (int)packh(a.x, b.x);                 // pos 0,1 = x0,x4
    v.y = (int)packh(a.y, b.y);
    v.z = (int)packh(a.z, b.z);
    v.w = (int)packh(a.w, b.w);
    *((int4*)dst + idx) = v;
}

// ---------- dequant W_gu -> f16 panels Bt[32][11264][64] (gate/up 16-col
// interleave, sigma values inside each word, linear word slots).
// v5: coalesced reads (64-col segments) AND coalesced writes (LDS-staged,
// 4 KB contiguous per store instruction). LDS slots XORed for bank safety. ----------
__global__ __launch_bounds__(256) void dequant_wgu(
    const uint32_t* __restrict__ W, const float* __restrict__ S,
    __half* __restrict__ Bt)
{
    __shared__ __half L[256 * 64];   // 32 KB
    const int kt = blockIdx.y;                       // 0..31
    const int t  = threadIdx.x;
    const int np = blockIdx.x * 256 + t;             // interleaved row
    const int sc = (np >> 5) * 16 + (np & 15) + (((np >> 4) & 1) ? IDIM : 0);
    uint32_t s2u = scale_s2u(S[(size_t)(kt >> 1) * (2 * IDIM) + sc]);
    #pragma unroll
    for (int j = 0; j < 8; ++j) {
        uint32_t w = W[(size_t)(kt * 8 + j) * (2 * IDIM) + sc];
        int4 d = dec8(w, s2u);
        *(int4*)&L[t * 64 + ((j ^ (t & 7)) << 3)] = d;   // bank-spread slot
    }
    __syncthreads();
    __half* dst = Bt + (size_t)kt * G1_KSB + (size_t)blockIdx.x * 256 * 64;
    #pragma unroll
    for (int k = 0; k < 8; ++k) {
        int c = k * 256 + t;                 // chunk: row=c>>3, word s=c&7
        int row = c >> 3, s = c & 7;
        int4 d = *(const int4*)&L[row * 64 + ((s ^ (row & 7)) << 3)];
        *(int4*)(dst + c * 8) = d;           // lane-contiguous 4 KB per instr
    }
}

// ---------- GEMM1: 256x128 tile, 512 thr, 8 waves (64x64 each), single-buffer
// 48 KB LDS (3 blocks/CU = 24 waves), pure gl_lds staging with per-lane
// source-swizzle (LDS dest linear; src slot s^(row&7)). Proven r5 structure. ----------
__global__ __launch_bounds__(512, 4) void gemm1_sx(
    const __half* __restrict__ A, const __half* __restrict__ Bt,
    __half* __restrict__ act)
{
    __shared__ __half Alds[256 * 64];   // 32 KB
    __shared__ __half Blds[128 * 64];   // 16 KB
    const int tid  = threadIdx.x;
    const int lane = tid & 63;
    const int wid  = tid >> 6;
    const int wm = wid >> 1;   // 0..3 -> rows wm*64
    const int wn = wid & 1;    // 0..1 -> cols wn*64
    const int m0 = blockIdx.y * 256;
    const int n0 = blockIdx.x * 128;

    f32x4 acc[4][4];
    #pragma unroll
    for (int i = 0; i < 4; ++i)
        #pragma unroll
        for (int j = 0; j < 4; ++j) acc[i][j] = f32x4{0.f, 0.f, 0.f, 0.f};

    const __half* srcA[4];
    const __half* srcB[2];
    #pragma unroll
    for (int i = 0; i < 4; ++i) {
        int u = i * 512 + tid, row = u >> 3, s = u & 7, sl = s ^ (row & 7);
        srcA[i] = A + (size_t)(m0 + row) * HDIM + sl * 8;
    }
    #pragma unroll
    for (int i = 0; i < 2; ++i) {
        int u = i * 512 + tid, row = u >> 3, s = u & 7, sl = s ^ (row & 7);
        srcB[i] = Bt + (size_t)(n0 + row) * 64 + sl * 8;
    }

    for (int kt = 0; kt < HDIM / 64; ++kt) {
        #pragma unroll
        for (int i = 0; i < 4; ++i)
            gl_lds16(srcA[i] + (size_t)kt * 64, (char*)Alds + (i * 512 + tid) * 16);
        #pragma unroll
        for (int i = 0; i < 2; ++i)
            gl_lds16(srcB[i] + (size_t)kt * G1_KSB, (char*)Blds + (i * 512 + tid) * 16);
        __syncthreads();
        #pragma unroll
        for (int ks = 0; ks < 2; ++ks) {
            f16x8 af[4], bf[4];
            const int kb = ks * 4 + (lane >> 4);
            #pragma unroll
            for (int mi = 0; mi < 4; ++mi) {
                int r = wm * 64 + mi * 16 + (lane & 15);
                af[mi] = *(const f16x8*)&Alds[r * 64 + ((kb ^ (r & 7)) << 3)];
            }
            #pragma unroll
            for (int ni = 0; ni < 4; ++ni) {
                int r = wn * 64 + ni * 16 + (lane & 15);
                bf[ni] = *(const f16x8*)&Blds[r * 64 + ((kb ^ (r & 7)) << 3)];
            }
            #pragma unroll
            for (int mi = 0; mi < 4; ++mi)
                #pragma unroll
                for (int ni = 0; ni < 4; ++ni)
                    acc[mi][ni] = __builtin_amdgcn_mfma_f32_16x16x32_f16(af[mi], bf[ni], acc[mi][ni], 0, 0, 0);
        }
        __syncthreads();
    }

    // epilogue: silu(gate)*up -> act (ni=2q gate, 2q+1 up; sigma col slot)
    #pragma unroll
    for (int mi = 0; mi < 4; ++mi) {
        #pragma unroll
        for (int q = 0; q < 2; ++q) {
            int gc = ((n0 + wn * 64 + q * 32) >> 5) * 16 + (lane & 15);
            int colstore = (gc & ~7) | (((gc & 3) << 1) | ((gc >> 2) & 1));
            #pragma unroll
            for (int r = 0; r < 4; ++r) {
                int m = m0 + wm * 64 + mi * 16 + (lane >> 4) * 4 + r;
                float gv = acc[mi][2 * q][r];
                float uv = acc[mi][2 * q + 1][r];
                float sig = 1.0f / (1.0f + __expf(-gv));
                act[(size_t)m * IDIM + colstore] = __float2half(gv * sig * uv);
            }
        }
    }
}

// ---------- round-1 fused-decode GEMM1 (fallback if ws too small) ----------
__global__ __launch_bounds__(256, 2) void gemm1_silu(
    const __half* __restrict__ A, const uint32_t* __restrict__ W,
    const float* __restrict__ S, __half* __restrict__ act)
{
    __shared__ __half Alds[BM * BK];
    __shared__ __half Blds[2][BN * BK];
    const int tid  = threadIdx.x;
    const int lane = tid & 63;
    const int wid  = tid >> 6;
    const int wm = wid >> 1, wn = wid & 1;
    const int m0 = blockIdx.y * BM;
    const int c0 = blockIdx.x * BN;

    f32x4 accg[4][4], accu[4][4];
    #pragma unroll
    for (int i = 0; i < 4; ++i)
        #pragma unroll
        for (int j = 0; j < 4; ++j) {
            accg[i][j] = f32x4{0.f, 0.f, 0.f, 0.f};
            accu[i][j] = f32x4{0.f, 0.f, 0.f, 0.f};
        }

    const int c = tid & 127;
    const int rbase = (tid >> 7) * 4;

    for (int kt = 0; kt < HDIM / BK; ++kt) {
        const int k0 = kt * BK;
        #pragma unroll
        for (int i = 0; i < 4; ++i) {
            int u = tid + i * 256;
            int row = u >> 3, kb = u & 7;
            int4 v = *(const int4*)(A + (size_t)(m0 + row) * HDIM + k0 + kb * 8);
            *(int4*)((char*)Alds + row * 128 + ((kb ^ (row & 7)) << 4)) = v;
        }
        const int g = k0 >> 7;
        #pragma unroll
        for (int p = 0; p < 2; ++p) {
            const int ncol = (p ? IDIM : 0) + c0 + c;
            uint32_t s2u = scale_s2u(S[(size_t)g * (2 * IDIM) + ncol]);
            #pragma unroll
            for (int i = 0; i < 4; ++i) {
                int rl = rbase + i;
                uint32_t w = W[(size_t)(kt * 8 + rl) * (2 * IDIM) + ncol];
                int4 d = dec8(w, s2u);
                *(int4*)((char*)&Blds[p][0] + c * 128 + ((rl ^ (c & 7)) << 4)) = d;
            }
        }
        __syncthreads();
        #pragma unroll
        for (int ks = 0; ks < 2; ++ks) {
            f16x8 af[4], bg[4], bu[4];
            const int kb = ks * 4 + (lane >> 4);
            #pragma unroll
            for (int mi = 0; mi < 4; ++mi) {
                int m = wm * 64 + mi * 16 + (lane & 15);
                af[mi] = *(const f16x8*)((const char*)Alds + m * 128 + ((kb ^ (m & 7)) << 4));
            }
            #pragma unroll
            for (int ni = 0; ni < 4; ++ni) {
                int n = wn * 64 + ni * 16 + (lane & 15);
                bg[ni] = *(const f16x8*)((const char*)&Blds[0][0] + n * 128 + ((kb ^ (n & 7)) << 4));
                bu[ni] = *(const f16x8*)((const char*)&Blds[1][0] + n * 128 + ((kb ^ (n & 7)) << 4));
            }
            #pragma unroll
            for (int mi = 0; mi < 4; ++mi)
                #pragma unroll
                for (int ni = 0; ni < 4; ++ni) {
                    accg[mi][ni] = __builtin_amdgcn_mfma_f32_16x16x32_f16(af[mi], bg[ni], accg[mi][ni], 0, 0, 0);
                    accu[mi][ni] = __builtin_amdgcn_mfma_f32_16x16x32_f16(af[mi], bu[ni], accu[mi][ni], 0, 0, 0);
                }
        }
        __syncthreads();
    }
    #pragma unroll
    for (int mi = 0; mi < 4; ++mi) {
        #pragma unroll
        for (int ni = 0; ni < 4; ++ni) {
            int nlog = c0 + wn * 64 + ni * 16 + (lane & 15);
            int ncol = (nlog & ~7) | (((nlog & 3) << 1) | ((nlog >> 2) & 1));
            #pragma unroll
            for (int r = 0; r < 4; ++r) {
                int m = m0 + wm * 64 + mi * 16 + (lane >> 4) * 4 + r;
                float gv = accg[mi][ni][r];
                float uv = accu[mi][ni][r];
                float sig = 1.0f / (1.0f + __expf(-gv));
                act[(size_t)m * IDIM + ncol] = __float2half(gv * sig * uv);
            }
        }
    }
}

// ---------- GEMM2 (fused decode, measured 90 us): out = moe + act @ deq(Wd) ----------
__global__ __launch_bounds__(256, 2) void gemm2_add(
    const __half* __restrict__ A, const uint32_t* __restrict__ W,
    const float* __restrict__ S, const float* __restrict__ moe,
    float* __restrict__ out)
{
    __shared__ __half Alds[BM * BK];
    __shared__ __half Blds[BN * BK];
    const int tid  = threadIdx.x;
    const int lane = tid & 63;
    const int wid  = tid >> 6;
    const int wm = wid >> 1, wn = wid & 1;
    const int m0 = blockIdx.y * BM;
    const int n0 = blockIdx.x * BN;

    f32x4 acc[4][4];
    #pragma unroll
    for (int i = 0; i < 4; ++i)
        #pragma unroll
        for (int j = 0; j < 4; ++j) acc[i][j] = f32x4{0.f, 0.f, 0.f, 0.f};

    const int c = tid & 127;
    const int rbase = (tid >> 7) * 4;

    for (int kt = 0; kt < IDIM / BK; ++kt) {
        const int k0 = kt * BK;
        #pragma unroll
        for (int i = 0; i < 4; ++i) {
            int u = tid + i * 256;
            int row = u >> 3, kb = u & 7;
            int4 v = *(const int4*)(A + (size_t)(m0 + row) * IDIM + k0 + kb * 8);
            *(int4*)((char*)Alds + row * 128 + ((kb ^ (row & 7)) << 4)) = v;
        }
        {
            const int g = k0 >> 7;
            const int ncol = n0 + c;
            uint32_t s2u = scale_s2u(S[(size_t)g * HDIM + ncol]);
            #pragma unroll
            for (int i = 0; i < 4; ++i) {
                int rl = rbase + i;
                uint32_t w = W[(size_t)(kt * 8 + rl) * HDIM + ncol];
                int4 d = dec8(w, s2u);
                *(int4*)((char*)Blds + c * 128 + ((rl ^ (c & 7)) << 4)) = d;
            }
        }
        __syncthreads();
        #pragma unroll
        for (int ks = 0; ks < 2; ++ks) {
            f16x8 af[4], bf[4];
            const int kb = ks * 4 + (lane >> 4);
            #pragma unroll
            for (int mi = 0; mi < 4; ++mi) {
                int m = wm * 64 + mi * 16 + (lane & 15);
                af[mi] = *(const f16x8*)((const char*)Alds + m * 128 + ((kb ^ (m & 7)) << 4));
            }
            #pragma unroll
            for (int ni = 0; ni < 4; ++ni) {
                int n = wn * 64 + ni * 16 + (lane & 15);
                bf[ni] = *(const f16x8*)((const char*)Blds + n * 128 + ((kb ^ (n & 7)) << 4));
            }
            #pragma unroll
            for (int mi = 0; mi < 4; ++mi)
                #pragma unroll
                for (int ni = 0; ni < 4; ++ni)
                    acc[mi][ni] = __builtin_amdgcn_mfma_f32_16x16x32_f16(af[mi], bf[ni], acc[mi][ni], 0, 0, 0);
        }
        __syncthreads();
    }
    #pragma unroll
    for (int mi = 0; mi < 4; ++mi) {
        #pragma unroll
        for (int ni = 0; ni < 4; ++ni) {
            int n = n0 + wn * 64 + ni * 16 + (lane & 15);
            #pragma unroll
            for (int r = 0; r < 4; ++r) {
                int m = m0 + wm * 64 + mi * 16 + (lane >> 4) * 4 + r;
                out[(size_t)m * HDIM + n] = moe[(size_t)m * HDIM + n] + acc[mi][ni][r];
            }
        }
    }
}

extern "C" void kernel_launch(void* const* d_in, const int* in_sizes, int n_in,
                              void* d_out, int out_size, void* d_ws, size_t ws_size,
                              hipStream_t stream) {
    const float*    hidden = (const float*)d_in[0];
    const float*    moe    = (const float*)d_in[1];
    const uint32_t* wgu    = (const uint32_t*)d_in[2];
    const float*    sgu    = (const float*)d_in[3];
    const uint32_t* wd     = (const uint32_t*)d_in[4];
    const float*    sd     = (const float*)d_in[5];
    float* out = (float*)d_out;

    const size_t sz_hidden = (size_t)TOKENS * HDIM * 2;      // 16.78 MB
    const size_t sz_act    = (size_t)TOKENS * IDIM * 2;      // 46.14 MB
    const size_t sz_wgu16  = (size_t)HDIM * 2 * IDIM * 2;    // 46.14 MB

    __half* hidden_f16 = (__half*)d_ws;
    __half* act        = (__half*)((char*)d_ws + sz_hidden);
    __half* wgu16      = (__half*)((char*)d_ws + sz_hidden + sz_act);

    const size_t need_g1 = sz_hidden + sz_act + sz_wgu16;    // 109 MB (proven available r5/r6)

    convert_hidden<<<dim3(TOKENS * HDIM / 8 / 256), dim3(256), 0, stream>>>(hidden, hidden_f16);

    if (ws_size >= need_g1) {
        dequant_wgu<<<dim3(G1_NP / 256, 32), dim3(256), 0, stream>>>(wgu, sgu, wgu16);
        gemm1_sx<<<dim3(G1_NP / 128, TOKENS / 256), dim3(512), 0, stream>>>(hidden_f16, wgu16, act);
    } else {
        gemm1_silu<<<dim3(IDIM / BN, TOKENS / BM), dim3(256), 0, stream>>>(hidden_f16, wgu, sgu, act);
    }

    gemm2_add<<<dim3(HDIM / BN, TOKENS / BM), dim3(256), 0, stream>>>(act, wd, sd, moe, out);
}